// Round 1
// baseline (3653.496 us; speedup 1.0000x reference)
//
#include <hip/hip_runtime.h>
#include <stdint.h>

#define PRE_K   6000
#define POST_K  1000
#define CAP     8192      // candidate buffer per batch
#define BINS    1024
#define MASKW   188       // ceil(6016/32) >= 6000 bits
#define NEGF    -1000000000.0f

// ---- helpers ----------------------------------------------------------------

__device__ __forceinline__ uint32_t orderf(float f) {
  // monotone float->uint mapping (larger float => larger uint)
  uint32_t u = __float_as_uint(f);
  return (u & 0x80000000u) ? ~u : (u | 0x80000000u);
}

__device__ __forceinline__ int score_bin(float sc) {
  int bin = (int)floorf((sc + 12.0f) * ((float)BINS / 24.0f));
  return bin < 0 ? 0 : (bin > BINS - 1 ? BINS - 1 : bin);
}

// full double-precision decode, matching the float64 numpy reference
__device__ __forceinline__ void decode_box(
    const float* __restrict__ anchors, const float* __restrict__ deltas,
    const int* __restrict__ isz, int n, int b,
    double& x1, double& y1, double& x2, double& y2, bool& valid) {
  double ax1 = (double)anchors[4 * n + 0], ay1 = (double)anchors[4 * n + 1];
  double ax2 = (double)anchors[4 * n + 2], ay2 = (double)anchors[4 * n + 3];
  double aw = ax2 - ax1, ah = ay2 - ay1;
  double acx = ax1 + 0.5 * aw, acy = ay1 + 0.5 * ah;
  double tx = (double)deltas[4 * n + 0], ty = (double)deltas[4 * n + 1];
  double tw = (double)deltas[4 * n + 2], th = (double)deltas[4 * n + 3];
  tw = tw < -10.0 ? -10.0 : (tw > 10.0 ? 10.0 : tw);
  th = th < -10.0 ? -10.0 : (th > 10.0 ? 10.0 : th);
  double px = acx + tx * aw, py = acy + ty * ah;
  double pw = aw * exp(tw), ph = ah * exp(th);
  double H = (double)isz[2 * b + 0], W = (double)isz[2 * b + 1];
  double wm = W - 1.0, hm = H - 1.0;
  x1 = px - 0.5 * pw; y1 = py - 0.5 * ph;
  x2 = px + 0.5 * pw; y2 = py + 0.5 * ph;
  x1 = fmin(fmax(x1, 0.0), wm); x2 = fmin(fmax(x2, 0.0), wm);
  y1 = fmin(fmax(y1, 0.0), hm); y2 = fmin(fmax(y2, 0.0), hm);
  valid = (x2 - x1 >= 16.0) && (y2 - y1 >= 16.0);
}

// ---- kernels ----------------------------------------------------------------

__global__ void k_init(uint32_t* hist, uint32_t* cnt, int B) {
  int i = blockIdx.x * blockDim.x + threadIdx.x;
  if (i < B * BINS) hist[i] = 0u;
  if (i < B) cnt[i] = 0u;
}

__global__ void k_score(const float* __restrict__ anchors,
                        const int* __restrict__ bix,
                        const int* __restrict__ isz,
                        const float* __restrict__ logits,
                        const float* __restrict__ deltas,
                        float* __restrict__ scores,
                        uint32_t* __restrict__ hist, int N) {
  int n = blockIdx.x * blockDim.x + threadIdx.x;
  if (n >= N) return;
  int b = bix[n];
  double x1, y1, x2, y2; bool valid;
  decode_box(anchors, deltas, isz, n, b, x1, y1, x2, y2, valid);
  float sc = valid ? logits[n] : NEGF;
  scores[n] = sc;
  if (valid) atomicAdd(&hist[b * BINS + score_bin(sc)], 1u);
}

__global__ void k_scan(const uint32_t* __restrict__ hist, uint32_t* __restrict__ bstar) {
  __shared__ uint32_t s[BINS];
  __shared__ int bs;
  int b = blockIdx.x, t = threadIdx.x;
  s[t] = hist[b * BINS + t];
  if (t == 0) bs = 0;
  __syncthreads();
  for (int off = 1; off < BINS; off <<= 1) {
    uint32_t v = (t + off < BINS) ? s[t + off] : 0u;
    __syncthreads();
    s[t] += v;
    __syncthreads();
  }
  if (s[t] >= PRE_K) atomicMax(&bs, t);
  __syncthreads();
  if (t == 0) bstar[b] = (uint32_t)bs;
}

__global__ void k_compact(const float* __restrict__ scores,
                          const int* __restrict__ bix,
                          const uint32_t* __restrict__ bstar,
                          uint32_t* __restrict__ cnt,
                          uint64_t* __restrict__ cand, int N) {
  int n = blockIdx.x * blockDim.x + threadIdx.x;
  if (n >= N) return;
  float sc = scores[n];
  if (sc <= 0.5f * NEGF) return;                 // invalid / NEG: never producible
  int b = bix[n];
  if ((uint32_t)score_bin(sc) < bstar[b]) return;
  uint32_t pos = atomicAdd(&cnt[b], 1u);
  if (pos < CAP)
    cand[(size_t)b * CAP + pos] =
        ((uint64_t)orderf(sc) << 32) | (uint64_t)(uint32_t)(~(uint32_t)n);
}

// exact ranking of <=8192 unique u64 keys per batch; grid = B*8 blocks x 1024
__global__ void k_rank(const uint64_t* __restrict__ cand,
                       const uint32_t* __restrict__ cnt,
                       int* __restrict__ sorted_n, int* __restrict__ Cnum) {
  int b = blockIdx.x >> 3, chunk = blockIdx.x & 7, t = threadIdx.x;
  int C = (int)min(cnt[b], (uint32_t)CAP);
  int i = chunk * 1024 + t;
  uint64_t ki = (i < C) ? cand[(size_t)b * CAP + i] : 0ull;
  __shared__ uint64_t tile[1024];
  int rank = 0;
  for (int base = 0; base < C; base += 1024) {
    int j = base + t;
    tile[t] = (j < C) ? cand[(size_t)b * CAP + j] : 0ull;
    __syncthreads();
    int lim = min(1024, C - base);
    for (int jj = 0; jj < lim; jj++) rank += (tile[jj] > ki) ? 1 : 0;
    __syncthreads();
  }
  if (i < C && rank < PRE_K)
    sorted_n[b * PRE_K + rank] = (int)(~(uint32_t)(ki & 0xFFFFFFFFull));
  if (chunk == 0 && t == 0) Cnum[b] = C < PRE_K ? C : PRE_K;
}

__global__ void k_gather(const float* __restrict__ anchors,
                         const float* __restrict__ deltas,
                         const int* __restrict__ isz,
                         const int* __restrict__ sorted_n,
                         const int* __restrict__ Cnum,
                         double* __restrict__ tbox, double* __restrict__ tarea,
                         int* __restrict__ top_n, int B) {
  int idx = blockIdx.x * blockDim.x + threadIdx.x;
  if (idx >= B * PRE_K) return;
  int b = idx / PRE_K, r = idx % PRE_K;
  if (r >= Cnum[b]) return;
  int n = sorted_n[idx];
  double x1, y1, x2, y2; bool valid;
  decode_box(anchors, deltas, isz, n, b, x1, y1, x2, y2, valid);
  tbox[(size_t)idx * 4 + 0] = x1;
  tbox[(size_t)idx * 4 + 1] = y1;
  tbox[(size_t)idx * 4 + 2] = x2;
  tbox[(size_t)idx * 4 + 3] = y2;
  tarea[idx] = (x2 - x1) * (y2 - y1);
  top_n[idx] = n;
}

// greedy NMS: picked index is the first unsuppressed (scores sorted desc) and
// is monotonically increasing -> ballot-scan frontier instead of full argmax.
__global__ void __launch_bounds__(1024) k_nms(const double* __restrict__ tbox,
                                              const double* __restrict__ tarea,
                                              const int* __restrict__ Cnum,
                                              int* __restrict__ keep,
                                              int* __restrict__ kept_count) {
  int b = blockIdx.x, t = threadIdx.x;
  int Ceff = Cnum[b];

  double bx[6][4], bar6[6];
  bool dead[6];
  for (int k = 0; k < 6; k++) {
    int r = t + k * 1024;
    if (r < Ceff) {
      const double* p = &tbox[((size_t)b * PRE_K + r) * 4];
      bx[k][0] = p[0]; bx[k][1] = p[1]; bx[k][2] = p[2]; bx[k][3] = p[3];
      bar6[k] = tarea[(size_t)b * PRE_K + r];
      dead[k] = false;
    } else {
      dead[k] = true;
      bx[k][0] = bx[k][1] = bx[k][2] = bx[k][3] = 0.0; bar6[k] = 0.0;
    }
  }

  __shared__ uint32_t sup[MASKW];
  __shared__ double bj[5];
  __shared__ int s_j;
  if (t < MASKW) {
    int base = t * 32;
    uint32_t m;
    if (base >= Ceff) m = 0xFFFFFFFFu;
    else if (base + 32 <= Ceff) m = 0u;
    else m = ~((1u << (Ceff - base)) - 1u);
    sup[t] = m;
  }
  __syncthreads();

  int kept = 0, cur = 0;
  while (kept < POST_K) {
    if (t < 64) {                       // wave 0 finds next survivor >= cur
      if (t == 0) s_j = -1;
      int w0 = cur >> 5;
      int found = 0;
      for (int basew = w0; basew < MASKW && !found; basew += 64) {
        int w = basew + t;
        uint32_t m = (w < MASKW) ? ~sup[w] : 0u;
        if (w == w0) m &= (0xFFFFFFFFu << (cur & 31));
        unsigned long long bal = __ballot(m != 0u);
        if (bal != 0ull) {
          int src = __builtin_ctzll(bal);
          if (t == src) s_j = w * 32 + __builtin_ctz(m);
          found = 1;
        }
      }
    }
    __syncthreads();
    int j = s_j;
    if (j < 0) break;
    if ((j & 1023) == t) {              // owner publishes box j via LDS
      int k = j >> 10;
      bj[0] = bx[k][0]; bj[1] = bx[k][1]; bj[2] = bx[k][2]; bj[3] = bx[k][3];
      bj[4] = bar6[k];
    }
    if (t == 0) keep[b * POST_K + kept] = j;
    __syncthreads();
    double jx1 = bj[0], jy1 = bj[1], jx2 = bj[2], jy2 = bj[3], ja = bj[4];
    for (int k = 0; k < 6; k++) {
      if (dead[k]) continue;
      int r = t + k * 1024;
      if (r <= j) { if (r == j) dead[k] = true; continue; }
      double ix1 = fmax(jx1, bx[k][0]);
      double iy1 = fmax(jy1, bx[k][1]);
      double ix2 = fmin(jx2, bx[k][2]);
      double iy2 = fmin(jy2, bx[k][3]);
      double iw = ix2 - ix1; iw = iw > 0.0 ? iw : 0.0;
      double ih = iy2 - iy1; ih = ih > 0.0 ? ih : 0.0;
      double inter = iw * ih;
      double iou = inter / (bar6[k] + ja - inter + 1e-9);
      if (iou > 0.7) {
        dead[k] = true;
        atomicOr(&sup[r >> 5], 1u << (r & 31));
      }
    }
    kept++;
    cur = j + 1;
    __syncthreads();
  }
  if (t == 0) kept_count[b] = kept;
}

__global__ void k_output(const int* __restrict__ keep,
                         const int* __restrict__ kept_count,
                         const int* __restrict__ top_n,
                         const double* __restrict__ tbox,
                         const float* __restrict__ logits,
                         const float* __restrict__ deltas,
                         float* __restrict__ out, int B) {
  int idx = blockIdx.x * blockDim.x + threadIdx.x;
  int M = B * POST_K;
  if (idx >= M) return;
  int b = idx / POST_K, s = idx % POST_K;
  float p0 = 0.f, p1 = 0.f, p2 = 0.f, p3 = 0.f;
  float ob = 0.f, d0 = 0.f, d1 = 0.f, d2 = 0.f, d3 = 0.f;
  float bi = -1.0f, okv = 0.0f;
  if (s < kept_count[b]) {
    int j = keep[b * POST_K + s];
    int n = top_n[b * PRE_K + j];
    const double* p = &tbox[((size_t)b * PRE_K + j) * 4];
    p0 = (float)p[0]; p1 = (float)p[1]; p2 = (float)p[2]; p3 = (float)p[3];
    ob = logits[n];
    d0 = deltas[4 * n + 0]; d1 = deltas[4 * n + 1];
    d2 = deltas[4 * n + 2]; d3 = deltas[4 * n + 3];
    bi = (float)b; okv = 1.0f;
  }
  out[idx * 4 + 0] = p0;            // props   [0, 4M)
  out[idx * 4 + 1] = p1;
  out[idx * 4 + 2] = p2;
  out[idx * 4 + 3] = p3;
  out[4 * M + idx] = bi;            // bidx    [4M, 5M)
  out[5 * M + idx] = ob;            // obj     [5M, 6M)
  out[6 * M + idx * 4 + 0] = d0;    // deltas  [6M, 10M)
  out[6 * M + idx * 4 + 1] = d1;
  out[6 * M + idx * 4 + 2] = d2;
  out[6 * M + idx * 4 + 3] = d3;
  out[10 * M + idx] = okv;          // keep_ok [10M, 11M)
}

// ---- launch -----------------------------------------------------------------

extern "C" void kernel_launch(void* const* d_in, const int* in_sizes, int n_in,
                              void* d_out, int out_size, void* d_ws, size_t ws_size,
                              hipStream_t stream) {
  const float* anchors = (const float*)d_in[0];
  const int*   bix     = (const int*)d_in[1];
  const int*   isz     = (const int*)d_in[2];
  const float* logits  = (const float*)d_in[3];
  const float* deltas  = (const float*)d_in[4];
  float* out = (float*)d_out;

  int N = in_sizes[1];
  int B = in_sizes[2] / 2;

  // workspace layout (8-byte-aligned sections first); ~9.3 MB total
  uintptr_t p = (uintptr_t)d_ws;
  double*   tbox   = (double*)p;    p += (size_t)B * PRE_K * 4 * sizeof(double);
  double*   tarea  = (double*)p;    p += (size_t)B * PRE_K * sizeof(double);
  uint64_t* cand   = (uint64_t*)p;  p += (size_t)B * CAP * sizeof(uint64_t);
  float*    scores = (float*)p;     p += (size_t)N * sizeof(float);
  uint32_t* hist   = (uint32_t*)p;  p += (size_t)B * BINS * sizeof(uint32_t);
  int*      sorted_n = (int*)p;     p += (size_t)B * PRE_K * sizeof(int);
  int*      top_n    = (int*)p;     p += (size_t)B * PRE_K * sizeof(int);
  int*      keep     = (int*)p;     p += (size_t)B * POST_K * sizeof(int);
  uint32_t* cnt      = (uint32_t*)p; p += (size_t)B * sizeof(uint32_t);
  uint32_t* bstar    = (uint32_t*)p; p += (size_t)B * sizeof(uint32_t);
  int*      Cnum     = (int*)p;      p += (size_t)B * sizeof(int);
  int*      kept_cnt = (int*)p;      p += (size_t)B * sizeof(int);
  (void)ws_size; (void)n_in; (void)out_size;

  int initN = B * BINS;
  k_init<<<(initN + 255) / 256, 256, 0, stream>>>(hist, cnt, B);
  k_score<<<(N + 255) / 256, 256, 0, stream>>>(anchors, bix, isz, logits, deltas,
                                               scores, hist, N);
  k_scan<<<B, BINS, 0, stream>>>(hist, bstar);
  k_compact<<<(N + 255) / 256, 256, 0, stream>>>(scores, bix, bstar, cnt, cand, N);
  k_rank<<<B * 8, 1024, 0, stream>>>(cand, cnt, sorted_n, Cnum);
  k_gather<<<(B * PRE_K + 255) / 256, 256, 0, stream>>>(anchors, deltas, isz,
                                                        sorted_n, Cnum, tbox,
                                                        tarea, top_n, B);
  k_nms<<<B, 1024, 0, stream>>>(tbox, tarea, Cnum, keep, kept_cnt);
  k_output<<<(B * POST_K + 255) / 256, 256, 0, stream>>>(keep, kept_cnt, top_n,
                                                         tbox, logits, deltas,
                                                         out, B);
}

// Round 2
// 2397.599 us; speedup vs baseline: 1.5238x; 1.5238x over previous
//
#include <hip/hip_runtime.h>
#include <stdint.h>

#define PRE_K   6000
#define POST_K  1000
#define CAP     8192      // candidate buffer per batch
#define BINS    1024
#define ROWS    6016      // 94*64, padded row count for NMS
#define CH      94        // ROWS/64 chunks
#define MASKW   188       // ROWS/32 mask words per row
#define NEGF    -1000000000.0f

// ---- helpers ----------------------------------------------------------------

__device__ __forceinline__ uint32_t orderf(float f) {
  uint32_t u = __float_as_uint(f);
  return (u & 0x80000000u) ? ~u : (u | 0x80000000u);
}

__device__ __forceinline__ int score_bin(float sc) {
  int bin = (int)floorf((sc + 12.0f) * ((float)BINS / 24.0f));
  return bin < 0 ? 0 : (bin > BINS - 1 ? BINS - 1 : bin);
}

// full double-precision decode, matching the float64 numpy reference
__device__ __forceinline__ void decode_box(
    const float* __restrict__ anchors, const float* __restrict__ deltas,
    const int* __restrict__ isz, int n, int b,
    double& x1, double& y1, double& x2, double& y2, bool& valid) {
  double ax1 = (double)anchors[4 * n + 0], ay1 = (double)anchors[4 * n + 1];
  double ax2 = (double)anchors[4 * n + 2], ay2 = (double)anchors[4 * n + 3];
  double aw = ax2 - ax1, ah = ay2 - ay1;
  double acx = ax1 + 0.5 * aw, acy = ay1 + 0.5 * ah;
  double tx = (double)deltas[4 * n + 0], ty = (double)deltas[4 * n + 1];
  double tw = (double)deltas[4 * n + 2], th = (double)deltas[4 * n + 3];
  tw = tw < -10.0 ? -10.0 : (tw > 10.0 ? 10.0 : tw);
  th = th < -10.0 ? -10.0 : (th > 10.0 ? 10.0 : th);
  double px = acx + tx * aw, py = acy + ty * ah;
  double pw = aw * exp(tw), ph = ah * exp(th);
  double H = (double)isz[2 * b + 0], W = (double)isz[2 * b + 1];
  double wm = W - 1.0, hm = H - 1.0;
  x1 = px - 0.5 * pw; y1 = py - 0.5 * ph;
  x2 = px + 0.5 * pw; y2 = py + 0.5 * ph;
  x1 = fmin(fmax(x1, 0.0), wm); x2 = fmin(fmax(x2, 0.0), wm);
  y1 = fmin(fmax(y1, 0.0), hm); y2 = fmin(fmax(y2, 0.0), hm);
  valid = (x2 - x1 >= 16.0) && (y2 - y1 >= 16.0);
}

// ---- kernels ----------------------------------------------------------------

__global__ void k_init(uint32_t* hist, uint32_t* cnt, int B) {
  int i = blockIdx.x * blockDim.x + threadIdx.x;
  if (i < B * BINS) hist[i] = 0u;
  if (i < B) cnt[i] = 0u;
}

__global__ void k_score(const float* __restrict__ anchors,
                        const int* __restrict__ bix,
                        const int* __restrict__ isz,
                        const float* __restrict__ logits,
                        const float* __restrict__ deltas,
                        float* __restrict__ scores,
                        uint32_t* __restrict__ hist, int N) {
  int n = blockIdx.x * blockDim.x + threadIdx.x;
  if (n >= N) return;
  int b = bix[n];
  double x1, y1, x2, y2; bool valid;
  decode_box(anchors, deltas, isz, n, b, x1, y1, x2, y2, valid);
  float sc = valid ? logits[n] : NEGF;
  scores[n] = sc;
  if (valid) atomicAdd(&hist[b * BINS + score_bin(sc)], 1u);
}

__global__ void k_scan(const uint32_t* __restrict__ hist, uint32_t* __restrict__ bstar) {
  __shared__ uint32_t s[BINS];
  __shared__ int bs;
  int b = blockIdx.x, t = threadIdx.x;
  s[t] = hist[b * BINS + t];
  if (t == 0) bs = 0;
  __syncthreads();
  for (int off = 1; off < BINS; off <<= 1) {
    uint32_t v = (t + off < BINS) ? s[t + off] : 0u;
    __syncthreads();
    s[t] += v;
    __syncthreads();
  }
  if (s[t] >= PRE_K) atomicMax(&bs, t);
  __syncthreads();
  if (t == 0) bstar[b] = (uint32_t)bs;
}

__global__ void k_compact(const float* __restrict__ scores,
                          const int* __restrict__ bix,
                          const uint32_t* __restrict__ bstar,
                          uint32_t* __restrict__ cnt,
                          uint64_t* __restrict__ cand, int N) {
  int n = blockIdx.x * blockDim.x + threadIdx.x;
  if (n >= N) return;
  float sc = scores[n];
  if (sc <= 0.5f * NEGF) return;
  int b = bix[n];
  if ((uint32_t)score_bin(sc) < bstar[b]) return;
  uint32_t pos = atomicAdd(&cnt[b], 1u);
  if (pos < CAP)
    cand[(size_t)b * CAP + pos] =
        ((uint64_t)orderf(sc) << 32) | (uint64_t)(uint32_t)(~(uint32_t)n);
}

// exact ranking of <=8192 unique u64 keys per batch; grid = B*8 blocks x 1024
__global__ void k_rank(const uint64_t* __restrict__ cand,
                       const uint32_t* __restrict__ cnt,
                       int* __restrict__ sorted_n, int* __restrict__ Cnum) {
  int b = blockIdx.x >> 3, chunk = blockIdx.x & 7, t = threadIdx.x;
  int C = (int)min(cnt[b], (uint32_t)CAP);
  int i = chunk * 1024 + t;
  uint64_t ki = (i < C) ? cand[(size_t)b * CAP + i] : 0ull;
  __shared__ uint64_t tile[1024];
  int rank = 0;
  for (int base = 0; base < C; base += 1024) {
    int j = base + t;
    tile[t] = (j < C) ? cand[(size_t)b * CAP + j] : 0ull;
    __syncthreads();
    int lim = min(1024, C - base);
    for (int jj = 0; jj < lim; jj++) rank += (tile[jj] > ki) ? 1 : 0;
    __syncthreads();
  }
  if (i < C && rank < PRE_K)
    sorted_n[b * PRE_K + rank] = (int)(~(uint32_t)(ki & 0xFFFFFFFFull));
  if (chunk == 0 && t == 0) Cnum[b] = C < PRE_K ? C : PRE_K;
}

__global__ void k_gather(const float* __restrict__ anchors,
                         const float* __restrict__ deltas,
                         const int* __restrict__ isz,
                         const int* __restrict__ sorted_n,
                         const int* __restrict__ Cnum,
                         double* __restrict__ tbox, double* __restrict__ tarea,
                         int* __restrict__ top_n, int B) {
  int idx = blockIdx.x * blockDim.x + threadIdx.x;
  if (idx >= B * PRE_K) return;
  int b = idx / PRE_K, r = idx % PRE_K;
  if (r >= Cnum[b]) return;
  int n = sorted_n[idx];
  double x1, y1, x2, y2; bool valid;
  decode_box(anchors, deltas, isz, n, b, x1, y1, x2, y2, valid);
  size_t row = (size_t)b * ROWS + r;
  tbox[row * 4 + 0] = x1;
  tbox[row * 4 + 1] = y1;
  tbox[row * 4 + 2] = x2;
  tbox[row * 4 + 3] = y2;
  tarea[row] = (x2 - x1) * (y2 - y1);
  top_n[idx] = n;
}

// Upper-triangular suppression bit-matrix: bit j of row i = (IoU(i,j)>0.7, j>i).
// grid = B*CH*CH blocks x 64 lanes; block (b, rc, cc) computes a 64x64 tile.
__global__ void __launch_bounds__(64) k_iou_mat(const double* __restrict__ tbox,
                                                const double* __restrict__ tarea,
                                                const int* __restrict__ Cnum,
                                                uint32_t* __restrict__ mask) {
  int blk = blockIdx.x;
  int cc = blk % CH;
  int rc = (blk / CH) % CH;
  int b  = blk / (CH * CH);
  if (cc < rc) return;                 // lower triangle never read
  int C = Cnum[b];
  if (rc * 64 >= C) return;            // rows pre-suppressed, never read
  int lane = threadIdx.x;

  __shared__ double cb[64][5];
  {
    size_t jrow = (size_t)b * ROWS + cc * 64 + lane;
    const double* pj = &tbox[jrow * 4];
    cb[lane][0] = pj[0]; cb[lane][1] = pj[1];
    cb[lane][2] = pj[2]; cb[lane][3] = pj[3];
    cb[lane][4] = tarea[jrow];
  }
  __syncthreads();

  int i = rc * 64 + lane;
  size_t irow = (size_t)b * ROWS + i;
  const double* pi = &tbox[irow * 4];
  double x1 = pi[0], y1 = pi[1], x2 = pi[2], y2 = pi[3];
  double ai = tarea[irow];

  uint32_t w0 = 0u, w1 = 0u;
  for (int jj = 0; jj < 64; jj++) {
    int jcol = cc * 64 + jj;
    double ix1 = fmax(x1, cb[jj][0]);
    double iy1 = fmax(y1, cb[jj][1]);
    double ix2 = fmin(x2, cb[jj][2]);
    double iy2 = fmin(y2, cb[jj][3]);
    double iw = ix2 - ix1; iw = iw > 0.0 ? iw : 0.0;
    double ih = iy2 - iy1; ih = ih > 0.0 ? ih : 0.0;
    double inter = iw * ih;
    // iou > 0.7  <=>  inter > 0.7*(ai+aj-inter+1e-9)   (denominator > 0)
    bool sup = (jcol > i) && (inter > 0.7 * (ai + cb[jj][4] - inter + 1e-9));
    if (jj < 32) w0 |= (uint32_t)sup << jj;
    else         w1 |= (uint32_t)sup << (jj - 32);
  }
  uint32_t* mr = &mask[irow * MASKW + 2 * cc];
  mr[0] = w0; mr[1] = w1;
}

// Sequential greedy resolve over 94 chunks of 64 rows; one wave per batch.
// Picks are strictly increasing in sorted order, so only the diagonal tile is
// needed for intra-chunk resolution; kept rows OR their mask row forward.
__global__ void __launch_bounds__(64) k_nms_reduce(const uint32_t* __restrict__ mask,
                                                   const int* __restrict__ Cnum,
                                                   int* __restrict__ keep,
                                                   int* __restrict__ kept_count) {
  int b = blockIdx.x, lane = threadIdx.x;
  int C = Cnum[b];
  const uint32_t* M = mask + (size_t)b * ROWS * MASKW;

  // suppression vector distributed: lane holds words lane, lane+64, lane+128
  uint32_t remv[3];
#pragma unroll
  for (int k = 0; k < 3; k++) {
    int w = lane + 64 * k;
    uint32_t v;
    if (w >= MASKW) v = 0xFFFFFFFFu;
    else {
      int base = w * 32;
      v = (base >= C) ? 0xFFFFFFFFu
          : ((base + 32 <= C) ? 0u : ~((1u << (C - base)) - 1u));
    }
    remv[k] = v;
  }

  int kept = 0;
  for (int c = 0; c < CH; c++) {
    int base = c * 64;
    if (base >= C) break;
    int w0i = 2 * c, w1i = 2 * c + 1;
    uint32_t r0 = (w0i < 64) ? remv[0] : ((w0i < 128) ? remv[1] : remv[2]);
    uint32_t lo = (uint32_t)__shfl((int)r0, w0i & 63, 64);
    uint32_t r1 = (w1i < 64) ? remv[0] : ((w1i < 128) ? remv[1] : remv[2]);
    uint32_t hi = (uint32_t)__shfl((int)r1, w1i & 63, 64);
    uint64_t sup = (uint64_t)lo | ((uint64_t)hi << 32);
    uint64_t alive = ~sup;
    if (alive == 0ull) continue;

    // diagonal-tile row for this lane's row (base+lane): words 2c, 2c+1
    const uint32_t* rp = M + (size_t)(base + lane) * MASKW + 2 * c;
    uint64_t diag = (uint64_t)rp[0] | ((uint64_t)rp[1] << 32);

    uint64_t m = alive, keptMask = 0ull;
    while (m) {
      int i = __builtin_ctzll(m);
      keptMask |= 1ull << i;
      uint64_t d = (uint64_t)__shfl((long long)diag, i, 64);
      sup |= d | (1ull << i);
      m &= ~sup;
    }

    if ((keptMask >> lane) & 1ull) {
      int pos = kept + __popcll(keptMask & ((1ull << lane) - 1ull));
      if (pos < POST_K) keep[b * POST_K + pos] = base + lane;
    }

    uint64_t km = keptMask;
    while (km) {
      int i = __builtin_ctzll(km); km &= km - 1ull;
      const uint32_t* rr = M + (size_t)(base + i) * MASKW;
#pragma unroll
      for (int k = 0; k < 3; k++) {
        int w = lane + 64 * k;
        if (w >= w0i && w < MASKW) remv[k] |= rr[w];
      }
    }
    kept += __popcll(keptMask);
    if (kept >= POST_K) break;
  }
  if (lane == 0) kept_count[b] = kept < POST_K ? kept : POST_K;
}

// ---- fallback serial NMS (used only if ws_size can't fit the bitmask) -------
__global__ void __launch_bounds__(1024) k_nms(const double* __restrict__ tbox,
                                              const double* __restrict__ tarea,
                                              const int* __restrict__ Cnum,
                                              int* __restrict__ keep,
                                              int* __restrict__ kept_count) {
  int b = blockIdx.x, t = threadIdx.x;
  int Ceff = Cnum[b];
  double bx[6][4], bar6[6];
  bool dead[6];
  for (int k = 0; k < 6; k++) {
    int r = t + k * 1024;
    if (r < Ceff) {
      const double* p = &tbox[((size_t)b * ROWS + r) * 4];
      bx[k][0] = p[0]; bx[k][1] = p[1]; bx[k][2] = p[2]; bx[k][3] = p[3];
      bar6[k] = tarea[(size_t)b * ROWS + r];
      dead[k] = false;
    } else { dead[k] = true; bx[k][0]=bx[k][1]=bx[k][2]=bx[k][3]=0.0; bar6[k]=0.0; }
  }
  __shared__ uint32_t supm[MASKW];
  __shared__ double bj[5];
  __shared__ int s_j;
  if (t < MASKW) {
    int base = t * 32;
    uint32_t m;
    if (base >= Ceff) m = 0xFFFFFFFFu;
    else if (base + 32 <= Ceff) m = 0u;
    else m = ~((1u << (Ceff - base)) - 1u);
    supm[t] = m;
  }
  __syncthreads();
  int kept = 0, cur = 0;
  while (kept < POST_K) {
    if (t < 64) {
      if (t == 0) s_j = -1;
      int w0 = cur >> 5;
      int found = 0;
      for (int basew = w0; basew < MASKW && !found; basew += 64) {
        int w = basew + t;
        uint32_t m = (w < MASKW) ? ~supm[w] : 0u;
        if (w == w0) m &= (0xFFFFFFFFu << (cur & 31));
        unsigned long long bal = __ballot(m != 0u);
        if (bal != 0ull) {
          int src = __builtin_ctzll(bal);
          if (t == src) s_j = w * 32 + __builtin_ctz(m);
          found = 1;
        }
      }
    }
    __syncthreads();
    int j = s_j;
    if (j < 0) break;
    if ((j & 1023) == t) {
      int k = j >> 10;
      bj[0]=bx[k][0]; bj[1]=bx[k][1]; bj[2]=bx[k][2]; bj[3]=bx[k][3]; bj[4]=bar6[k];
    }
    if (t == 0) keep[b * POST_K + kept] = j;
    __syncthreads();
    double jx1=bj[0], jy1=bj[1], jx2=bj[2], jy2=bj[3], ja=bj[4];
    for (int k = 0; k < 6; k++) {
      if (dead[k]) continue;
      int r = t + k * 1024;
      if (r <= j) { if (r == j) dead[k] = true; continue; }
      double ix1 = fmax(jx1, bx[k][0]);
      double iy1 = fmax(jy1, bx[k][1]);
      double ix2 = fmin(jx2, bx[k][2]);
      double iy2 = fmin(jy2, bx[k][3]);
      double iw = ix2 - ix1; iw = iw > 0.0 ? iw : 0.0;
      double ih = iy2 - iy1; ih = ih > 0.0 ? ih : 0.0;
      double inter = iw * ih;
      double iou = inter / (bar6[k] + ja - inter + 1e-9);
      if (iou > 0.7) { dead[k] = true; atomicOr(&supm[r >> 5], 1u << (r & 31)); }
    }
    kept++; cur = j + 1;
    __syncthreads();
  }
  if (t == 0) kept_count[b] = kept;
}

__global__ void k_output(const int* __restrict__ keep,
                         const int* __restrict__ kept_count,
                         const int* __restrict__ top_n,
                         const double* __restrict__ tbox,
                         const float* __restrict__ logits,
                         const float* __restrict__ deltas,
                         float* __restrict__ out, int B) {
  int idx = blockIdx.x * blockDim.x + threadIdx.x;
  int M = B * POST_K;
  if (idx >= M) return;
  int b = idx / POST_K, s = idx % POST_K;
  float p0 = 0.f, p1 = 0.f, p2 = 0.f, p3 = 0.f;
  float ob = 0.f, d0 = 0.f, d1 = 0.f, d2 = 0.f, d3 = 0.f;
  float bi = -1.0f, okv = 0.0f;
  if (s < kept_count[b]) {
    int j = keep[b * POST_K + s];
    int n = top_n[b * PRE_K + j];
    const double* p = &tbox[((size_t)b * ROWS + j) * 4];
    p0 = (float)p[0]; p1 = (float)p[1]; p2 = (float)p[2]; p3 = (float)p[3];
    ob = logits[n];
    d0 = deltas[4 * n + 0]; d1 = deltas[4 * n + 1];
    d2 = deltas[4 * n + 2]; d3 = deltas[4 * n + 3];
    bi = (float)b; okv = 1.0f;
  }
  out[idx * 4 + 0] = p0;
  out[idx * 4 + 1] = p1;
  out[idx * 4 + 2] = p2;
  out[idx * 4 + 3] = p3;
  out[4 * M + idx] = bi;
  out[5 * M + idx] = ob;
  out[6 * M + idx * 4 + 0] = d0;
  out[6 * M + idx * 4 + 1] = d1;
  out[6 * M + idx * 4 + 2] = d2;
  out[6 * M + idx * 4 + 3] = d3;
  out[10 * M + idx] = okv;
}

// ---- launch -----------------------------------------------------------------

extern "C" void kernel_launch(void* const* d_in, const int* in_sizes, int n_in,
                              void* d_out, int out_size, void* d_ws, size_t ws_size,
                              hipStream_t stream) {
  const float* anchors = (const float*)d_in[0];
  const int*   bix     = (const int*)d_in[1];
  const int*   isz     = (const int*)d_in[2];
  const float* logits  = (const float*)d_in[3];
  const float* deltas  = (const float*)d_in[4];
  float* out = (float*)d_out;

  int N = in_sizes[1];
  int B = in_sizes[2] / 2;

  uintptr_t p = (uintptr_t)d_ws;
  double*   tbox   = (double*)p;    p += (size_t)B * ROWS * 4 * sizeof(double);
  double*   tarea  = (double*)p;    p += (size_t)B * ROWS * sizeof(double);
  uint64_t* cand   = (uint64_t*)p;  p += (size_t)B * CAP * sizeof(uint64_t);
  float*    scores = (float*)p;     p += (size_t)N * sizeof(float);
  uint32_t* hist   = (uint32_t*)p;  p += (size_t)B * BINS * sizeof(uint32_t);
  int*      sorted_n = (int*)p;     p += (size_t)B * PRE_K * sizeof(int);
  int*      top_n    = (int*)p;     p += (size_t)B * PRE_K * sizeof(int);
  int*      keep     = (int*)p;     p += (size_t)B * POST_K * sizeof(int);
  uint32_t* cnt      = (uint32_t*)p; p += (size_t)B * sizeof(uint32_t);
  uint32_t* bstar    = (uint32_t*)p; p += (size_t)B * sizeof(uint32_t);
  int*      Cnum     = (int*)p;      p += (size_t)B * sizeof(int);
  int*      kept_cnt = (int*)p;      p += (size_t)B * sizeof(int);
  p = (p + 255) & ~(uintptr_t)255;
  uint32_t* mask     = (uint32_t*)p; p += (size_t)B * ROWS * MASKW * sizeof(uint32_t);
  size_t need = p - (uintptr_t)d_ws;
  bool use_mask = (ws_size >= need);
  (void)n_in; (void)out_size;

  int initN = B * BINS;
  k_init<<<(initN + 255) / 256, 256, 0, stream>>>(hist, cnt, B);
  k_score<<<(N + 255) / 256, 256, 0, stream>>>(anchors, bix, isz, logits, deltas,
                                               scores, hist, N);
  k_scan<<<B, BINS, 0, stream>>>(hist, bstar);
  k_compact<<<(N + 255) / 256, 256, 0, stream>>>(scores, bix, bstar, cnt, cand, N);
  k_rank<<<B * 8, 1024, 0, stream>>>(cand, cnt, sorted_n, Cnum);
  k_gather<<<(B * PRE_K + 255) / 256, 256, 0, stream>>>(anchors, deltas, isz,
                                                        sorted_n, Cnum, tbox,
                                                        tarea, top_n, B);
  if (use_mask) {
    k_iou_mat<<<B * CH * CH, 64, 0, stream>>>(tbox, tarea, Cnum, mask);
    k_nms_reduce<<<B, 64, 0, stream>>>(mask, Cnum, keep, kept_cnt);
  } else {
    k_nms<<<B, 1024, 0, stream>>>(tbox, tarea, Cnum, keep, kept_cnt);
  }
  k_output<<<(B * POST_K + 255) / 256, 256, 0, stream>>>(keep, kept_cnt, top_n,
                                                         tbox, logits, deltas,
                                                         out, B);
}

// Round 3
// 821.345 us; speedup vs baseline: 4.4482x; 2.9191x over previous
//
#include <hip/hip_runtime.h>
#include <stdint.h>

#define PRE_K   6000
#define POST_K  1000
#define CAP     8192      // candidate buffer per batch
#define BINS    1024
#define ROWS    6016      // 94*64, padded row count for NMS
#define CH      94        // ROWS/64 chunks
#define MASKW   188       // ROWS/32 mask words per row
#define NEGF    -1000000000.0f

// ---- helpers ----------------------------------------------------------------

__device__ __forceinline__ uint32_t orderf(float f) {
  uint32_t u = __float_as_uint(f);
  return (u & 0x80000000u) ? ~u : (u | 0x80000000u);
}

__device__ __forceinline__ int score_bin(float sc) {
  int bin = (int)floorf((sc + 12.0f) * ((float)BINS / 24.0f));
  return bin < 0 ? 0 : (bin > BINS - 1 ? BINS - 1 : bin);
}

// full double-precision decode, matching the float64 numpy reference
__device__ __forceinline__ void decode_box(
    const float* __restrict__ anchors, const float* __restrict__ deltas,
    const int* __restrict__ isz, int n, int b,
    double& x1, double& y1, double& x2, double& y2, bool& valid) {
  double ax1 = (double)anchors[4 * n + 0], ay1 = (double)anchors[4 * n + 1];
  double ax2 = (double)anchors[4 * n + 2], ay2 = (double)anchors[4 * n + 3];
  double aw = ax2 - ax1, ah = ay2 - ay1;
  double acx = ax1 + 0.5 * aw, acy = ay1 + 0.5 * ah;
  double tx = (double)deltas[4 * n + 0], ty = (double)deltas[4 * n + 1];
  double tw = (double)deltas[4 * n + 2], th = (double)deltas[4 * n + 3];
  tw = tw < -10.0 ? -10.0 : (tw > 10.0 ? 10.0 : tw);
  th = th < -10.0 ? -10.0 : (th > 10.0 ? 10.0 : th);
  double px = acx + tx * aw, py = acy + ty * ah;
  double pw = aw * exp(tw), ph = ah * exp(th);
  double H = (double)isz[2 * b + 0], W = (double)isz[2 * b + 1];
  double wm = W - 1.0, hm = H - 1.0;
  x1 = px - 0.5 * pw; y1 = py - 0.5 * ph;
  x2 = px + 0.5 * pw; y2 = py + 0.5 * ph;
  x1 = fmin(fmax(x1, 0.0), wm); x2 = fmin(fmax(x2, 0.0), wm);
  y1 = fmin(fmax(y1, 0.0), hm); y2 = fmin(fmax(y2, 0.0), hm);
  valid = (x2 - x1 >= 16.0) && (y2 - y1 >= 16.0);
}

// ---- kernels ----------------------------------------------------------------

__global__ void k_init(uint32_t* hist, uint32_t* cnt, int B) {
  int i = blockIdx.x * blockDim.x + threadIdx.x;
  if (i < B * BINS) hist[i] = 0u;
  if (i < B) cnt[i] = 0u;
}

__global__ void k_score(const float* __restrict__ anchors,
                        const int* __restrict__ bix,
                        const int* __restrict__ isz,
                        const float* __restrict__ logits,
                        const float* __restrict__ deltas,
                        float* __restrict__ scores,
                        uint32_t* __restrict__ hist, int N) {
  int n = blockIdx.x * blockDim.x + threadIdx.x;
  if (n >= N) return;
  int b = bix[n];
  double x1, y1, x2, y2; bool valid;
  decode_box(anchors, deltas, isz, n, b, x1, y1, x2, y2, valid);
  float sc = valid ? logits[n] : NEGF;
  scores[n] = sc;
  if (valid) atomicAdd(&hist[b * BINS + score_bin(sc)], 1u);
}

__global__ void k_scan(const uint32_t* __restrict__ hist, uint32_t* __restrict__ bstar) {
  __shared__ uint32_t s[BINS];
  __shared__ int bs;
  int b = blockIdx.x, t = threadIdx.x;
  s[t] = hist[b * BINS + t];
  if (t == 0) bs = 0;
  __syncthreads();
  for (int off = 1; off < BINS; off <<= 1) {
    uint32_t v = (t + off < BINS) ? s[t + off] : 0u;
    __syncthreads();
    s[t] += v;
    __syncthreads();
  }
  if (s[t] >= PRE_K) atomicMax(&bs, t);
  __syncthreads();
  if (t == 0) bstar[b] = (uint32_t)bs;
}

// Block-aggregated compaction: each block spans 8192 contiguous elements
// (<=2 distinct batches since batch_indices is sorted), counts candidates in
// LDS, then does ONE returning global atomicAdd per (block,batch).
__global__ void __launch_bounds__(1024) k_compact(const float* __restrict__ scores,
                                                  const int* __restrict__ bix,
                                                  const uint32_t* __restrict__ bstar,
                                                  uint32_t* __restrict__ cnt,
                                                  uint64_t* __restrict__ cand, int N) {
  const int SPAN = 8192;
  int start = blockIdx.x * SPAN;
  int end = start + SPAN < N ? start + SPAN : N;
  __shared__ uint32_t lcnt[8], lbase[8];
  if (threadIdx.x < 8) lcnt[threadIdx.x] = 0u;
  __syncthreads();

  bool     predv[8];
  uint64_t keyv[8];
  uint32_t lposv[8];
  int      bv[8];
  int nt = 0;
  for (int base = start; base < end; base += 1024, nt++) {
    int n = base + (int)threadIdx.x;
    bool pred = false; int b = 0; uint64_t key = 0ull; uint32_t lp = 0u;
    if (n < end) {
      float sc = scores[n];
      if (sc > 0.5f * NEGF) {
        b = bix[n];
        if ((uint32_t)score_bin(sc) >= bstar[b]) {
          pred = true;
          key = ((uint64_t)orderf(sc) << 32) | (uint64_t)(uint32_t)(~(uint32_t)n);
          lp = atomicAdd(&lcnt[b], 1u);
        }
      }
    }
    predv[nt] = pred; keyv[nt] = key; lposv[nt] = lp; bv[nt] = b;
  }
  __syncthreads();
  if (threadIdx.x < 8) {
    uint32_t c = lcnt[threadIdx.x];
    lbase[threadIdx.x] = c ? atomicAdd(&cnt[threadIdx.x], c) : 0u;
  }
  __syncthreads();
  for (int k = 0; k < nt; k++) {
    if (predv[k]) {
      uint32_t pos = lbase[bv[k]] + lposv[k];
      if (pos < CAP) cand[(size_t)bv[k] * CAP + pos] = keyv[k];
    }
  }
}

// exact ranking of <=8192 unique u64 keys per batch; grid = B*8 blocks x 1024
__global__ void k_rank(const uint64_t* __restrict__ cand,
                       const uint32_t* __restrict__ cnt,
                       int* __restrict__ sorted_n, int* __restrict__ Cnum) {
  int b = blockIdx.x >> 3, chunk = blockIdx.x & 7, t = threadIdx.x;
  int C = (int)min(cnt[b], (uint32_t)CAP);
  int i = chunk * 1024 + t;
  uint64_t ki = (i < C) ? cand[(size_t)b * CAP + i] : 0ull;
  __shared__ uint64_t tile[1024];
  int rank = 0;
  for (int base = 0; base < C; base += 1024) {
    int j = base + t;
    tile[t] = (j < C) ? cand[(size_t)b * CAP + j] : 0ull;
    __syncthreads();
    int lim = min(1024, C - base);
    for (int jj = 0; jj < lim; jj++) rank += (tile[jj] > ki) ? 1 : 0;
    __syncthreads();
  }
  if (i < C && rank < PRE_K)
    sorted_n[b * PRE_K + rank] = (int)(~(uint32_t)(ki & 0xFFFFFFFFull));
  if (chunk == 0 && t == 0) Cnum[b] = C < PRE_K ? C : PRE_K;
}

__global__ void k_gather(const float* __restrict__ anchors,
                         const float* __restrict__ deltas,
                         const int* __restrict__ isz,
                         const int* __restrict__ sorted_n,
                         const int* __restrict__ Cnum,
                         double* __restrict__ tbox, double* __restrict__ tarea,
                         int* __restrict__ top_n, int B) {
  int idx = blockIdx.x * blockDim.x + threadIdx.x;
  if (idx >= B * PRE_K) return;
  int b = idx / PRE_K, r = idx % PRE_K;
  if (r >= Cnum[b]) return;
  int n = sorted_n[idx];
  double x1, y1, x2, y2; bool valid;
  decode_box(anchors, deltas, isz, n, b, x1, y1, x2, y2, valid);
  size_t row = (size_t)b * ROWS + r;
  tbox[row * 4 + 0] = x1;
  tbox[row * 4 + 1] = y1;
  tbox[row * 4 + 2] = x2;
  tbox[row * 4 + 3] = y2;
  tarea[row] = (x2 - x1) * (y2 - y1);
  top_n[idx] = n;
}

// Upper-triangular suppression bit-matrix: bit j of row i = (IoU(i,j)>0.7, j>i).
// grid = B*CH*CH blocks x 64 lanes; block (b, rc, cc) computes a 64x64 tile.
__global__ void __launch_bounds__(64) k_iou_mat(const double* __restrict__ tbox,
                                                const double* __restrict__ tarea,
                                                const int* __restrict__ Cnum,
                                                uint32_t* __restrict__ mask) {
  int blk = blockIdx.x;
  int cc = blk % CH;
  int rc = (blk / CH) % CH;
  int b  = blk / (CH * CH);
  if (cc < rc) return;                 // lower triangle never read
  int C = Cnum[b];
  if (rc * 64 >= C) return;            // rows pre-suppressed, never read
  int lane = threadIdx.x;

  // 48B per column box: x1,y1,x2,y2,area,pad -> b128 + b64 LDS reads
  __shared__ double cb[64][6];
  {
    size_t jrow = (size_t)b * ROWS + cc * 64 + lane;
    const double* pj = &tbox[jrow * 4];
    cb[lane][0] = pj[0]; cb[lane][1] = pj[1];
    cb[lane][2] = pj[2]; cb[lane][3] = pj[3];
    cb[lane][4] = tarea[jrow];
  }
  __syncthreads();

  int i = rc * 64 + lane;
  size_t irow = (size_t)b * ROWS + i;
  const double* pi = &tbox[irow * 4];
  double x1 = pi[0], y1 = pi[1], x2 = pi[2], y2 = pi[3];
  double ai = tarea[irow];

  uint32_t w0 = 0u, w1 = 0u;
  for (int jj = 0; jj < 64; jj++) {
    int jcol = cc * 64 + jj;
    double4 cbox = *(const double4*)&cb[jj][0];  // one ds_read_b128 x2
    double carea = cb[jj][4];
    double ix1 = fmax(x1, cbox.x);
    double iy1 = fmax(y1, cbox.y);
    double ix2 = fmin(x2, cbox.z);
    double iy2 = fmin(y2, cbox.w);
    double iw = ix2 - ix1; iw = iw > 0.0 ? iw : 0.0;
    double ih = iy2 - iy1; ih = ih > 0.0 ? ih : 0.0;
    double inter = iw * ih;
    // iou > 0.7  <=>  inter > 0.7*(ai+aj-inter+1e-9)   (denominator > 0)
    bool sup = (jcol > i) && (inter > 0.7 * (ai + carea - inter + 1e-9));
    if (jj < 32) w0 |= (uint32_t)sup << jj;
    else         w1 |= (uint32_t)sup << (jj - 32);
  }
  uint32_t* mr = &mask[irow * MASKW + 2 * cc];
  mr[0] = w0; mr[1] = w1;
}

// Sequential greedy resolve over chunks of 64 rows; one 256-thread block per
// batch. Thread t owns suppression word t; kept-row mask ORs are 8-wide
// batched independent loads; wave0 runs the pick chain with diag prefetch.
__global__ void __launch_bounds__(256) k_nms_reduce(const uint32_t* __restrict__ mask,
                                                    const int* __restrict__ Cnum,
                                                    int* __restrict__ keep,
                                                    int* __restrict__ kept_count) {
  int b = blockIdx.x;
  int t = threadIdx.x;
  int wave = t >> 6, lane = t & 63;
  int C = Cnum[b];
  const uint32_t* M = mask + (size_t)b * ROWS * MASKW;

  // distributed suppression vector: thread t owns word t (t < MASKW)
  uint32_t remv = 0xFFFFFFFFu;
  if (t < MASKW) {
    int wb = t * 32;
    remv = (wb >= C) ? 0xFFFFFFFFu
           : ((wb + 32 <= C) ? 0u : ~((1u << (C - wb)) - 1u));
  }

  __shared__ uint32_t s_sup[2];
  __shared__ uint64_t s_kept;

  // wave0: prefetch diag tile words for chunk 0
  uint32_t d0 = 0u, d1 = 0u;
  if (wave == 0) {
    const uint32_t* rp = M + (size_t)lane * MASKW;
    uint2 v = *(const uint2*)rp;
    d0 = v.x; d1 = v.y;
  }

  int kept = 0;
  for (int c = 0; c < CH; c++) {
    int base = c * 64;
    if (base >= C) break;

    if (t == 2 * c || t == 2 * c + 1) s_sup[t & 1] = remv;
    __syncthreads();

    if (wave == 0) {
      uint64_t sup = (uint64_t)s_sup[0] | ((uint64_t)s_sup[1] << 32);
      uint64_t diag = (uint64_t)d0 | ((uint64_t)d1 << 32);
      // issue prefetch for next chunk's diag (addresses static)
      int cn = (c + 1 < CH) ? c + 1 : c;
      const uint32_t* rpn = M + (size_t)(cn * 64 + lane) * MASKW + 2 * cn;
      uint2 vn = *(const uint2*)rpn;

      uint64_t keptMask = 0ull;
      uint64_t alive = ~sup;
      uint64_t m = alive;
      while (m) {
        int i = __builtin_ctzll(m);
        keptMask |= 1ull << i;
        uint64_t d = (uint64_t)__shfl((long long)diag, i, 64);
        sup |= d | (1ull << i);
        m = alive & ~sup;
      }
      if (lane == 0) s_kept = keptMask;
      if ((keptMask >> lane) & 1ull) {
        int pos = kept + __popcll(keptMask & ((1ull << lane) - 1ull));
        if (pos < POST_K) keep[b * POST_K + pos] = base + lane;
      }
      d0 = vn.x; d1 = vn.y;
    }
    __syncthreads();

    uint64_t keptMask = s_kept;
    if (t < MASKW && t >= 2 * c && keptMask) {
      uint64_t km = keptMask;
      while (km) {
        int i0, i1 = -1, i2 = -1, i3 = -1, i4 = -1, i5 = -1, i6 = -1, i7 = -1;
        i0 = __builtin_ctzll(km); km &= km - 1ull;
        if (km) { i1 = __builtin_ctzll(km); km &= km - 1ull; }
        if (km) { i2 = __builtin_ctzll(km); km &= km - 1ull; }
        if (km) { i3 = __builtin_ctzll(km); km &= km - 1ull; }
        if (km) { i4 = __builtin_ctzll(km); km &= km - 1ull; }
        if (km) { i5 = __builtin_ctzll(km); km &= km - 1ull; }
        if (km) { i6 = __builtin_ctzll(km); km &= km - 1ull; }
        if (km) { i7 = __builtin_ctzll(km); km &= km - 1ull; }
        uint32_t v0 = M[(size_t)(base + i0) * MASKW + t];
        uint32_t v1 = (i1 >= 0) ? M[(size_t)(base + i1) * MASKW + t] : 0u;
        uint32_t v2 = (i2 >= 0) ? M[(size_t)(base + i2) * MASKW + t] : 0u;
        uint32_t v3 = (i3 >= 0) ? M[(size_t)(base + i3) * MASKW + t] : 0u;
        uint32_t v4 = (i4 >= 0) ? M[(size_t)(base + i4) * MASKW + t] : 0u;
        uint32_t v5 = (i5 >= 0) ? M[(size_t)(base + i5) * MASKW + t] : 0u;
        uint32_t v6 = (i6 >= 0) ? M[(size_t)(base + i6) * MASKW + t] : 0u;
        uint32_t v7 = (i7 >= 0) ? M[(size_t)(base + i7) * MASKW + t] : 0u;
        remv |= (v0 | v1) | (v2 | v3) | (v4 | v5) | (v6 | v7);
      }
    }
    kept += __popcll(keptMask);
    if (kept >= POST_K) break;
  }
  if (t == 0) kept_count[b] = kept < POST_K ? kept : POST_K;
}

__global__ void k_output(const int* __restrict__ keep,
                         const int* __restrict__ kept_count,
                         const int* __restrict__ top_n,
                         const double* __restrict__ tbox,
                         const float* __restrict__ logits,
                         const float* __restrict__ deltas,
                         float* __restrict__ out, int B) {
  int idx = blockIdx.x * blockDim.x + threadIdx.x;
  int M = B * POST_K;
  if (idx >= M) return;
  int b = idx / POST_K, s = idx % POST_K;
  float p0 = 0.f, p1 = 0.f, p2 = 0.f, p3 = 0.f;
  float ob = 0.f, d0 = 0.f, d1 = 0.f, d2 = 0.f, d3 = 0.f;
  float bi = -1.0f, okv = 0.0f;
  if (s < kept_count[b]) {
    int j = keep[b * POST_K + s];
    int n = top_n[b * PRE_K + j];
    const double* p = &tbox[((size_t)b * ROWS + j) * 4];
    p0 = (float)p[0]; p1 = (float)p[1]; p2 = (float)p[2]; p3 = (float)p[3];
    ob = logits[n];
    d0 = deltas[4 * n + 0]; d1 = deltas[4 * n + 1];
    d2 = deltas[4 * n + 2]; d3 = deltas[4 * n + 3];
    bi = (float)b; okv = 1.0f;
  }
  out[idx * 4 + 0] = p0;
  out[idx * 4 + 1] = p1;
  out[idx * 4 + 2] = p2;
  out[idx * 4 + 3] = p3;
  out[4 * M + idx] = bi;
  out[5 * M + idx] = ob;
  out[6 * M + idx * 4 + 0] = d0;
  out[6 * M + idx * 4 + 1] = d1;
  out[6 * M + idx * 4 + 2] = d2;
  out[6 * M + idx * 4 + 3] = d3;
  out[10 * M + idx] = okv;
}

// ---- launch -----------------------------------------------------------------

extern "C" void kernel_launch(void* const* d_in, const int* in_sizes, int n_in,
                              void* d_out, int out_size, void* d_ws, size_t ws_size,
                              hipStream_t stream) {
  const float* anchors = (const float*)d_in[0];
  const int*   bix     = (const int*)d_in[1];
  const int*   isz     = (const int*)d_in[2];
  const float* logits  = (const float*)d_in[3];
  const float* deltas  = (const float*)d_in[4];
  float* out = (float*)d_out;

  int N = in_sizes[1];
  int B = in_sizes[2] / 2;

  uintptr_t p = (uintptr_t)d_ws;
  double*   tbox   = (double*)p;    p += (size_t)B * ROWS * 4 * sizeof(double);
  double*   tarea  = (double*)p;    p += (size_t)B * ROWS * sizeof(double);
  uint64_t* cand   = (uint64_t*)p;  p += (size_t)B * CAP * sizeof(uint64_t);
  float*    scores = (float*)p;     p += (size_t)N * sizeof(float);
  uint32_t* hist   = (uint32_t*)p;  p += (size_t)B * BINS * sizeof(uint32_t);
  int*      sorted_n = (int*)p;     p += (size_t)B * PRE_K * sizeof(int);
  int*      top_n    = (int*)p;     p += (size_t)B * PRE_K * sizeof(int);
  int*      keep     = (int*)p;     p += (size_t)B * POST_K * sizeof(int);
  uint32_t* cnt      = (uint32_t*)p; p += (size_t)B * sizeof(uint32_t);
  uint32_t* bstar    = (uint32_t*)p; p += (size_t)B * sizeof(uint32_t);
  int*      Cnum     = (int*)p;      p += (size_t)B * sizeof(int);
  int*      kept_cnt = (int*)p;      p += (size_t)B * sizeof(int);
  p = (p + 255) & ~(uintptr_t)255;
  uint32_t* mask     = (uint32_t*)p; p += (size_t)B * ROWS * MASKW * sizeof(uint32_t);
  (void)ws_size; (void)n_in; (void)out_size;

  int initN = B * BINS;
  k_init<<<(initN + 255) / 256, 256, 0, stream>>>(hist, cnt, B);
  k_score<<<(N + 255) / 256, 256, 0, stream>>>(anchors, bix, isz, logits, deltas,
                                               scores, hist, N);
  k_scan<<<B, BINS, 0, stream>>>(hist, bstar);
  k_compact<<<(N + 8191) / 8192, 1024, 0, stream>>>(scores, bix, bstar, cnt, cand, N);
  k_rank<<<B * 8, 1024, 0, stream>>>(cand, cnt, sorted_n, Cnum);
  k_gather<<<(B * PRE_K + 255) / 256, 256, 0, stream>>>(anchors, deltas, isz,
                                                        sorted_n, Cnum, tbox,
                                                        tarea, top_n, B);
  k_iou_mat<<<B * CH * CH, 64, 0, stream>>>(tbox, tarea, Cnum, mask);
  k_nms_reduce<<<B, 256, 0, stream>>>(mask, Cnum, keep, kept_cnt);
  k_output<<<(B * POST_K + 255) / 256, 256, 0, stream>>>(keep, kept_cnt, top_n,
                                                         tbox, logits, deltas,
                                                         out, B);
}

// Round 4
// 539.295 us; speedup vs baseline: 6.7746x; 1.5230x over previous
//
#include <hip/hip_runtime.h>
#include <stdint.h>

#define PRE_K   6000
#define POST_K  1000
#define CAP     8192      // candidate buffer per batch
#define BINS    1024
#define ROWS    6016      // 94*64, padded row count for NMS
#define CH      94        // ROWS/64 chunks
#define MASKW   188       // ROWS/32 mask words per row
#define NEGF    -1000000000.0f

// ---- helpers ----------------------------------------------------------------

__device__ __forceinline__ uint32_t orderf(float f) {
  uint32_t u = __float_as_uint(f);
  return (u & 0x80000000u) ? ~u : (u | 0x80000000u);
}

__device__ __forceinline__ int score_bin(float sc) {
  int bin = (int)floorf((sc + 12.0f) * ((float)BINS / 24.0f));
  return bin < 0 ? 0 : (bin > BINS - 1 ? BINS - 1 : bin);
}

// scatter adjacent (popular) bins across different 64B L2 lines
__device__ __forceinline__ int bin_slot(int bin) {
  return ((bin & 15) << 6) | (bin >> 4);
}

// full double-precision decode, matching the float64 numpy reference
__device__ __forceinline__ void decode_box(
    const float* __restrict__ anchors, const float* __restrict__ deltas,
    const int* __restrict__ isz, int n, int b,
    double& x1, double& y1, double& x2, double& y2, bool& valid) {
  double ax1 = (double)anchors[4 * n + 0], ay1 = (double)anchors[4 * n + 1];
  double ax2 = (double)anchors[4 * n + 2], ay2 = (double)anchors[4 * n + 3];
  double aw = ax2 - ax1, ah = ay2 - ay1;
  double acx = ax1 + 0.5 * aw, acy = ay1 + 0.5 * ah;
  double tx = (double)deltas[4 * n + 0], ty = (double)deltas[4 * n + 1];
  double tw = (double)deltas[4 * n + 2], th = (double)deltas[4 * n + 3];
  tw = tw < -10.0 ? -10.0 : (tw > 10.0 ? 10.0 : tw);
  th = th < -10.0 ? -10.0 : (th > 10.0 ? 10.0 : th);
  double px = acx + tx * aw, py = acy + ty * ah;
  double pw = aw * exp(tw), ph = ah * exp(th);
  double H = (double)isz[2 * b + 0], W = (double)isz[2 * b + 1];
  double wm = W - 1.0, hm = H - 1.0;
  x1 = px - 0.5 * pw; y1 = py - 0.5 * ph;
  x2 = px + 0.5 * pw; y2 = py + 0.5 * ph;
  x1 = fmin(fmax(x1, 0.0), wm); x2 = fmin(fmax(x2, 0.0), wm);
  y1 = fmin(fmax(y1, 0.0), hm); y2 = fmin(fmax(y2, 0.0), hm);
  valid = (x2 - x1 >= 16.0) && (y2 - y1 >= 16.0);
}

// ---- kernels ----------------------------------------------------------------

__global__ void k_init(uint32_t* hist, uint32_t* cnt, int B) {
  int i = blockIdx.x * blockDim.x + threadIdx.x;
  if (i < B * BINS) hist[i] = 0u;
  if (i < B) cnt[i] = 0u;
}

// Decode + validity + LDS-privatized histogram. Each block owns a contiguous
// span of 4096 elements; batch_indices sorted => <=2 batches per span (rare
// middle batches fall back to direct global atomics).
__global__ void __launch_bounds__(256) k_score(const float* __restrict__ anchors,
                                               const int* __restrict__ bix,
                                               const int* __restrict__ isz,
                                               const float* __restrict__ logits,
                                               const float* __restrict__ deltas,
                                               float* __restrict__ scores,
                                               uint32_t* __restrict__ hist, int N) {
  const int SPAN = 4096;
  int start = blockIdx.x * SPAN;
  int end = start + SPAN < N ? start + SPAN : N;
  __shared__ uint32_t lh[2][BINS];
  for (int i = threadIdx.x; i < 2 * BINS; i += 256) ((uint32_t*)lh)[i] = 0u;
  __shared__ int s_b0, s_b1;
  if (threadIdx.x == 0) { s_b0 = bix[start]; s_b1 = bix[end - 1]; }
  __syncthreads();
  int b0 = s_b0, b1 = s_b1;

  for (int n = start + (int)threadIdx.x; n < end; n += 256) {
    int b = bix[n];
    double x1, y1, x2, y2; bool valid;
    decode_box(anchors, deltas, isz, n, b, x1, y1, x2, y2, valid);
    float sc = valid ? logits[n] : NEGF;
    scores[n] = sc;
    if (valid) {
      int bin = score_bin(sc);
      if (b == b0)      atomicAdd(&lh[0][bin], 1u);
      else if (b == b1) atomicAdd(&lh[1][bin], 1u);
      else              atomicAdd(&hist[b * BINS + bin_slot(bin)], 1u);
    }
  }
  __syncthreads();
  for (int bin = threadIdx.x; bin < BINS; bin += 256) {
    uint32_t c0 = lh[0][bin];
    if (c0) atomicAdd(&hist[b0 * BINS + bin_slot(bin)], c0);
    if (b1 != b0) {
      uint32_t c1 = lh[1][bin];
      if (c1) atomicAdd(&hist[b1 * BINS + bin_slot(bin)], c1);
    }
  }
}

__global__ void k_scan(const uint32_t* __restrict__ hist, uint32_t* __restrict__ bstar) {
  __shared__ uint32_t s[BINS];
  __shared__ int bs;
  int b = blockIdx.x, t = threadIdx.x;
  s[t] = hist[b * BINS + bin_slot(t)];
  if (t == 0) bs = 0;
  __syncthreads();
  for (int off = 1; off < BINS; off <<= 1) {
    uint32_t v = (t + off < BINS) ? s[t + off] : 0u;
    __syncthreads();
    s[t] += v;
    __syncthreads();
  }
  if (s[t] >= PRE_K) atomicMax(&bs, t);
  __syncthreads();
  if (t == 0) bstar[b] = (uint32_t)bs;
}

// Block-aggregated compaction: each block spans 8192 contiguous elements
// (<=2 distinct batches since batch_indices is sorted), counts candidates in
// LDS, then does ONE returning global atomicAdd per (block,batch).
__global__ void __launch_bounds__(1024) k_compact(const float* __restrict__ scores,
                                                  const int* __restrict__ bix,
                                                  const uint32_t* __restrict__ bstar,
                                                  uint32_t* __restrict__ cnt,
                                                  uint64_t* __restrict__ cand, int N) {
  const int SPAN = 8192;
  int start = blockIdx.x * SPAN;
  int end = start + SPAN < N ? start + SPAN : N;
  __shared__ uint32_t lcnt[8], lbase[8];
  if (threadIdx.x < 8) lcnt[threadIdx.x] = 0u;
  __syncthreads();

  bool     predv[8];
  uint64_t keyv[8];
  uint32_t lposv[8];
  int      bv[8];
  int nt = 0;
  for (int base = start; base < end; base += 1024, nt++) {
    int n = base + (int)threadIdx.x;
    bool pred = false; int b = 0; uint64_t key = 0ull; uint32_t lp = 0u;
    if (n < end) {
      float sc = scores[n];
      if (sc > 0.5f * NEGF) {
        b = bix[n];
        if ((uint32_t)score_bin(sc) >= bstar[b]) {
          pred = true;
          key = ((uint64_t)orderf(sc) << 32) | (uint64_t)(uint32_t)(~(uint32_t)n);
          lp = atomicAdd(&lcnt[b], 1u);
        }
      }
    }
    predv[nt] = pred; keyv[nt] = key; lposv[nt] = lp; bv[nt] = b;
  }
  __syncthreads();
  if (threadIdx.x < 8) {
    uint32_t c = lcnt[threadIdx.x];
    lbase[threadIdx.x] = c ? atomicAdd(&cnt[threadIdx.x], c) : 0u;
  }
  __syncthreads();
  for (int k = 0; k < nt; k++) {
    if (predv[k]) {
      uint32_t pos = lbase[bv[k]] + lposv[k];
      if (pos < CAP) cand[(size_t)bv[k] * CAP + pos] = keyv[k];
    }
  }
}

// exact ranking of <=8192 unique u64 keys per batch; grid = B*8 blocks x 1024
__global__ void k_rank(const uint64_t* __restrict__ cand,
                       const uint32_t* __restrict__ cnt,
                       int* __restrict__ sorted_n, int* __restrict__ Cnum) {
  int b = blockIdx.x >> 3, chunk = blockIdx.x & 7, t = threadIdx.x;
  int C = (int)min(cnt[b], (uint32_t)CAP);
  int i = chunk * 1024 + t;
  uint64_t ki = (i < C) ? cand[(size_t)b * CAP + i] : 0ull;
  __shared__ uint64_t tile[1024];
  int rank = 0;
  for (int base = 0; base < C; base += 1024) {
    int j = base + t;
    tile[t] = (j < C) ? cand[(size_t)b * CAP + j] : 0ull;
    __syncthreads();
    int lim = min(1024, C - base);
    for (int jj = 0; jj < lim; jj++) rank += (tile[jj] > ki) ? 1 : 0;
    __syncthreads();
  }
  if (i < C && rank < PRE_K)
    sorted_n[b * PRE_K + rank] = (int)(~(uint32_t)(ki & 0xFFFFFFFFull));
  if (chunk == 0 && t == 0) Cnum[b] = C < PRE_K ? C : PRE_K;
}

__global__ void k_gather(const float* __restrict__ anchors,
                         const float* __restrict__ deltas,
                         const int* __restrict__ isz,
                         const int* __restrict__ sorted_n,
                         const int* __restrict__ Cnum,
                         double* __restrict__ tbox, double* __restrict__ tarea,
                         int* __restrict__ top_n, int B) {
  int idx = blockIdx.x * blockDim.x + threadIdx.x;
  if (idx >= B * PRE_K) return;
  int b = idx / PRE_K, r = idx % PRE_K;
  if (r >= Cnum[b]) return;
  int n = sorted_n[idx];
  double x1, y1, x2, y2; bool valid;
  decode_box(anchors, deltas, isz, n, b, x1, y1, x2, y2, valid);
  size_t row = (size_t)b * ROWS + r;
  tbox[row * 4 + 0] = x1;
  tbox[row * 4 + 1] = y1;
  tbox[row * 4 + 2] = x2;
  tbox[row * 4 + 3] = y2;
  tarea[row] = (x2 - x1) * (y2 - y1);
  top_n[idx] = n;
}

// Upper-triangular suppression bit-matrix: bit j of row i = (IoU(i,j)>0.7, j>i).
// grid = B*CH*CH blocks x 64 lanes; block (b, rc, cc) computes a 64x64 tile.
__global__ void __launch_bounds__(64) k_iou_mat(const double* __restrict__ tbox,
                                                const double* __restrict__ tarea,
                                                const int* __restrict__ Cnum,
                                                uint32_t* __restrict__ mask) {
  int blk = blockIdx.x;
  int cc = blk % CH;
  int rc = (blk / CH) % CH;
  int b  = blk / (CH * CH);
  if (cc < rc) return;                 // lower triangle never read
  int C = Cnum[b];
  if (rc * 64 >= C) return;            // rows pre-suppressed, never read
  int lane = threadIdx.x;

  // 48B per column box: x1,y1,x2,y2,area,pad -> b128 + b64 LDS reads
  __shared__ double cb[64][6];
  {
    size_t jrow = (size_t)b * ROWS + cc * 64 + lane;
    const double* pj = &tbox[jrow * 4];
    cb[lane][0] = pj[0]; cb[lane][1] = pj[1];
    cb[lane][2] = pj[2]; cb[lane][3] = pj[3];
    cb[lane][4] = tarea[jrow];
  }
  __syncthreads();

  int i = rc * 64 + lane;
  size_t irow = (size_t)b * ROWS + i;
  const double* pi = &tbox[irow * 4];
  double x1 = pi[0], y1 = pi[1], x2 = pi[2], y2 = pi[3];
  double ai = tarea[irow];

  uint32_t w0 = 0u, w1 = 0u;
  for (int jj = 0; jj < 64; jj++) {
    int jcol = cc * 64 + jj;
    double4 cbox = *(const double4*)&cb[jj][0];  // one ds_read_b128 x2
    double carea = cb[jj][4];
    double ix1 = fmax(x1, cbox.x);
    double iy1 = fmax(y1, cbox.y);
    double ix2 = fmin(x2, cbox.z);
    double iy2 = fmin(y2, cbox.w);
    double iw = ix2 - ix1; iw = iw > 0.0 ? iw : 0.0;
    double ih = iy2 - iy1; ih = ih > 0.0 ? ih : 0.0;
    double inter = iw * ih;
    // iou > 0.7  <=>  inter > 0.7*(ai+aj-inter+1e-9)   (denominator > 0)
    bool sup = (jcol > i) && (inter > 0.7 * (ai + carea - inter + 1e-9));
    if (jj < 32) w0 |= (uint32_t)sup << jj;
    else         w1 |= (uint32_t)sup << (jj - 32);
  }
  uint32_t* mr = &mask[irow * MASKW + 2 * cc];
  mr[0] = w0; mr[1] = w1;
}

// Sequential greedy resolve over chunks of 64 rows; one 256-thread block per
// batch. Thread t owns suppression word t; kept-row mask ORs are 8-wide
// batched independent loads; wave0 runs the pick chain with diag prefetch.
__global__ void __launch_bounds__(256) k_nms_reduce(const uint32_t* __restrict__ mask,
                                                    const int* __restrict__ Cnum,
                                                    int* __restrict__ keep,
                                                    int* __restrict__ kept_count) {
  int b = blockIdx.x;
  int t = threadIdx.x;
  int wave = t >> 6, lane = t & 63;
  int C = Cnum[b];
  const uint32_t* M = mask + (size_t)b * ROWS * MASKW;

  // distributed suppression vector: thread t owns word t (t < MASKW)
  uint32_t remv = 0xFFFFFFFFu;
  if (t < MASKW) {
    int wb = t * 32;
    remv = (wb >= C) ? 0xFFFFFFFFu
           : ((wb + 32 <= C) ? 0u : ~((1u << (C - wb)) - 1u));
  }

  __shared__ uint32_t s_sup[2];
  __shared__ uint64_t s_kept;

  // wave0: prefetch diag tile words for chunk 0
  uint32_t d0 = 0u, d1 = 0u;
  if (wave == 0) {
    const uint32_t* rp = M + (size_t)lane * MASKW;
    uint2 v = *(const uint2*)rp;
    d0 = v.x; d1 = v.y;
  }

  int kept = 0;
  for (int c = 0; c < CH; c++) {
    int base = c * 64;
    if (base >= C) break;

    if (t == 2 * c || t == 2 * c + 1) s_sup[t & 1] = remv;
    __syncthreads();

    if (wave == 0) {
      uint64_t sup = (uint64_t)s_sup[0] | ((uint64_t)s_sup[1] << 32);
      uint64_t diag = (uint64_t)d0 | ((uint64_t)d1 << 32);
      // issue prefetch for next chunk's diag (addresses static)
      int cn = (c + 1 < CH) ? c + 1 : c;
      const uint32_t* rpn = M + (size_t)(cn * 64 + lane) * MASKW + 2 * cn;
      uint2 vn = *(const uint2*)rpn;

      uint64_t keptMask = 0ull;
      uint64_t alive = ~sup;
      uint64_t m = alive;
      while (m) {
        int i = __builtin_ctzll(m);
        keptMask |= 1ull << i;
        uint64_t d = (uint64_t)__shfl((long long)diag, i, 64);
        sup |= d | (1ull << i);
        m = alive & ~sup;
      }
      if (lane == 0) s_kept = keptMask;
      if ((keptMask >> lane) & 1ull) {
        int pos = kept + __popcll(keptMask & ((1ull << lane) - 1ull));
        if (pos < POST_K) keep[b * POST_K + pos] = base + lane;
      }
      d0 = vn.x; d1 = vn.y;
    }
    __syncthreads();

    uint64_t keptMask = s_kept;
    if (t < MASKW && t >= 2 * c && keptMask) {
      uint64_t km = keptMask;
      while (km) {
        int i0, i1 = -1, i2 = -1, i3 = -1, i4 = -1, i5 = -1, i6 = -1, i7 = -1;
        i0 = __builtin_ctzll(km); km &= km - 1ull;
        if (km) { i1 = __builtin_ctzll(km); km &= km - 1ull; }
        if (km) { i2 = __builtin_ctzll(km); km &= km - 1ull; }
        if (km) { i3 = __builtin_ctzll(km); km &= km - 1ull; }
        if (km) { i4 = __builtin_ctzll(km); km &= km - 1ull; }
        if (km) { i5 = __builtin_ctzll(km); km &= km - 1ull; }
        if (km) { i6 = __builtin_ctzll(km); km &= km - 1ull; }
        if (km) { i7 = __builtin_ctzll(km); km &= km - 1ull; }
        uint32_t v0 = M[(size_t)(base + i0) * MASKW + t];
        uint32_t v1 = (i1 >= 0) ? M[(size_t)(base + i1) * MASKW + t] : 0u;
        uint32_t v2 = (i2 >= 0) ? M[(size_t)(base + i2) * MASKW + t] : 0u;
        uint32_t v3 = (i3 >= 0) ? M[(size_t)(base + i3) * MASKW + t] : 0u;
        uint32_t v4 = (i4 >= 0) ? M[(size_t)(base + i4) * MASKW + t] : 0u;
        uint32_t v5 = (i5 >= 0) ? M[(size_t)(base + i5) * MASKW + t] : 0u;
        uint32_t v6 = (i6 >= 0) ? M[(size_t)(base + i6) * MASKW + t] : 0u;
        uint32_t v7 = (i7 >= 0) ? M[(size_t)(base + i7) * MASKW + t] : 0u;
        remv |= (v0 | v1) | (v2 | v3) | (v4 | v5) | (v6 | v7);
      }
    }
    kept += __popcll(keptMask);
    if (kept >= POST_K) break;
  }
  if (t == 0) kept_count[b] = kept < POST_K ? kept : POST_K;
}

__global__ void k_output(const int* __restrict__ keep,
                         const int* __restrict__ kept_count,
                         const int* __restrict__ top_n,
                         const double* __restrict__ tbox,
                         const float* __restrict__ logits,
                         const float* __restrict__ deltas,
                         float* __restrict__ out, int B) {
  int idx = blockIdx.x * blockDim.x + threadIdx.x;
  int M = B * POST_K;
  if (idx >= M) return;
  int b = idx / POST_K, s = idx % POST_K;
  float p0 = 0.f, p1 = 0.f, p2 = 0.f, p3 = 0.f;
  float ob = 0.f, d0 = 0.f, d1 = 0.f, d2 = 0.f, d3 = 0.f;
  float bi = -1.0f, okv = 0.0f;
  if (s < kept_count[b]) {
    int j = keep[b * POST_K + s];
    int n = top_n[b * PRE_K + j];
    const double* p = &tbox[((size_t)b * ROWS + j) * 4];
    p0 = (float)p[0]; p1 = (float)p[1]; p2 = (float)p[2]; p3 = (float)p[3];
    ob = logits[n];
    d0 = deltas[4 * n + 0]; d1 = deltas[4 * n + 1];
    d2 = deltas[4 * n + 2]; d3 = deltas[4 * n + 3];
    bi = (float)b; okv = 1.0f;
  }
  out[idx * 4 + 0] = p0;
  out[idx * 4 + 1] = p1;
  out[idx * 4 + 2] = p2;
  out[idx * 4 + 3] = p3;
  out[4 * M + idx] = bi;
  out[5 * M + idx] = ob;
  out[6 * M + idx * 4 + 0] = d0;
  out[6 * M + idx * 4 + 1] = d1;
  out[6 * M + idx * 4 + 2] = d2;
  out[6 * M + idx * 4 + 3] = d3;
  out[10 * M + idx] = okv;
}

// ---- launch -----------------------------------------------------------------

extern "C" void kernel_launch(void* const* d_in, const int* in_sizes, int n_in,
                              void* d_out, int out_size, void* d_ws, size_t ws_size,
                              hipStream_t stream) {
  const float* anchors = (const float*)d_in[0];
  const int*   bix     = (const int*)d_in[1];
  const int*   isz     = (const int*)d_in[2];
  const float* logits  = (const float*)d_in[3];
  const float* deltas  = (const float*)d_in[4];
  float* out = (float*)d_out;

  int N = in_sizes[1];
  int B = in_sizes[2] / 2;

  uintptr_t p = (uintptr_t)d_ws;
  double*   tbox   = (double*)p;    p += (size_t)B * ROWS * 4 * sizeof(double);
  double*   tarea  = (double*)p;    p += (size_t)B * ROWS * sizeof(double);
  uint64_t* cand   = (uint64_t*)p;  p += (size_t)B * CAP * sizeof(uint64_t);
  float*    scores = (float*)p;     p += (size_t)N * sizeof(float);
  uint32_t* hist   = (uint32_t*)p;  p += (size_t)B * BINS * sizeof(uint32_t);
  int*      sorted_n = (int*)p;     p += (size_t)B * PRE_K * sizeof(int);
  int*      top_n    = (int*)p;     p += (size_t)B * PRE_K * sizeof(int);
  int*      keep     = (int*)p;     p += (size_t)B * POST_K * sizeof(int);
  uint32_t* cnt      = (uint32_t*)p; p += (size_t)B * sizeof(uint32_t);
  uint32_t* bstar    = (uint32_t*)p; p += (size_t)B * sizeof(uint32_t);
  int*      Cnum     = (int*)p;      p += (size_t)B * sizeof(int);
  int*      kept_cnt = (int*)p;      p += (size_t)B * sizeof(int);
  p = (p + 255) & ~(uintptr_t)255;
  uint32_t* mask     = (uint32_t*)p; p += (size_t)B * ROWS * MASKW * sizeof(uint32_t);
  (void)ws_size; (void)n_in; (void)out_size;

  int initN = B * BINS;
  k_init<<<(initN + 255) / 256, 256, 0, stream>>>(hist, cnt, B);
  k_score<<<(N + 4095) / 4096, 256, 0, stream>>>(anchors, bix, isz, logits, deltas,
                                                 scores, hist, N);
  k_scan<<<B, BINS, 0, stream>>>(hist, bstar);
  k_compact<<<(N + 8191) / 8192, 1024, 0, stream>>>(scores, bix, bstar, cnt, cand, N);
  k_rank<<<B * 8, 1024, 0, stream>>>(cand, cnt, sorted_n, Cnum);
  k_gather<<<(B * PRE_K + 255) / 256, 256, 0, stream>>>(anchors, deltas, isz,
                                                        sorted_n, Cnum, tbox,
                                                        tarea, top_n, B);
  k_iou_mat<<<B * CH * CH, 64, 0, stream>>>(tbox, tarea, Cnum, mask);
  k_nms_reduce<<<B, 256, 0, stream>>>(mask, Cnum, keep, kept_cnt);
  k_output<<<(B * POST_K + 255) / 256, 256, 0, stream>>>(keep, kept_cnt, top_n,
                                                         tbox, logits, deltas,
                                                         out, B);
}

// Round 5
// 490.786 us; speedup vs baseline: 7.4442x; 1.0988x over previous
//
#include <hip/hip_runtime.h>
#include <stdint.h>

#define PRE_K   6000
#define POST_K  1000
#define CAP     8192      // candidate buffer per batch
#define BINS    1024
#define ROWS    6016      // 94*64, padded row count for NMS
#define CH      94        // ROWS/64 chunks
#define MASKW   188       // ROWS/32 mask words per row
#define NEGF    -1000000000.0f

// ---- helpers ----------------------------------------------------------------

__device__ __forceinline__ uint32_t orderf(float f) {
  uint32_t u = __float_as_uint(f);
  return (u & 0x80000000u) ? ~u : (u | 0x80000000u);
}

__device__ __forceinline__ int score_bin(float sc) {
  int bin = (int)floorf((sc + 12.0f) * ((float)BINS / 24.0f));
  return bin < 0 ? 0 : (bin > BINS - 1 ? BINS - 1 : bin);
}

// scatter adjacent (popular) bins across different 64B L2 lines
__device__ __forceinline__ int bin_slot(int bin) {
  return ((bin & 15) << 6) | (bin >> 4);
}

// full double-precision decode, matching the float64 numpy reference
__device__ __forceinline__ void decode_box(
    const float* __restrict__ anchors, const float* __restrict__ deltas,
    const int* __restrict__ isz, int n, int b,
    double& x1, double& y1, double& x2, double& y2, bool& valid) {
  double ax1 = (double)anchors[4 * n + 0], ay1 = (double)anchors[4 * n + 1];
  double ax2 = (double)anchors[4 * n + 2], ay2 = (double)anchors[4 * n + 3];
  double aw = ax2 - ax1, ah = ay2 - ay1;
  double acx = ax1 + 0.5 * aw, acy = ay1 + 0.5 * ah;
  double tx = (double)deltas[4 * n + 0], ty = (double)deltas[4 * n + 1];
  double tw = (double)deltas[4 * n + 2], th = (double)deltas[4 * n + 3];
  tw = tw < -10.0 ? -10.0 : (tw > 10.0 ? 10.0 : tw);
  th = th < -10.0 ? -10.0 : (th > 10.0 ? 10.0 : th);
  double px = acx + tx * aw, py = acy + ty * ah;
  double pw = aw * exp(tw), ph = ah * exp(th);
  double H = (double)isz[2 * b + 0], W = (double)isz[2 * b + 1];
  double wm = W - 1.0, hm = H - 1.0;
  x1 = px - 0.5 * pw; y1 = py - 0.5 * ph;
  x2 = px + 0.5 * pw; y2 = py + 0.5 * ph;
  x1 = fmin(fmax(x1, 0.0), wm); x2 = fmin(fmax(x2, 0.0), wm);
  y1 = fmin(fmax(y1, 0.0), hm); y2 = fmin(fmax(y2, 0.0), hm);
  valid = (x2 - x1 >= 16.0) && (y2 - y1 >= 16.0);
}

// ---- kernels ----------------------------------------------------------------

__global__ void k_init(uint32_t* hist, uint32_t* cnt, int B) {
  int i = blockIdx.x * blockDim.x + threadIdx.x;
  if (i < B * BINS) hist[i] = 0u;
  if (i < B) cnt[i] = 0u;
}

// Decode + validity + LDS-privatized histogram. Each block owns a contiguous
// span of 4096 elements; batch_indices sorted => <=2 batches per span (rare
// middle batches fall back to direct global atomics).
__global__ void __launch_bounds__(256) k_score(const float* __restrict__ anchors,
                                               const int* __restrict__ bix,
                                               const int* __restrict__ isz,
                                               const float* __restrict__ logits,
                                               const float* __restrict__ deltas,
                                               float* __restrict__ scores,
                                               uint32_t* __restrict__ hist, int N) {
  const int SPAN = 4096;
  int start = blockIdx.x * SPAN;
  int end = start + SPAN < N ? start + SPAN : N;
  __shared__ uint32_t lh[2][BINS];
  for (int i = threadIdx.x; i < 2 * BINS; i += 256) ((uint32_t*)lh)[i] = 0u;
  __shared__ int s_b0, s_b1;
  if (threadIdx.x == 0) { s_b0 = bix[start]; s_b1 = bix[end - 1]; }
  __syncthreads();
  int b0 = s_b0, b1 = s_b1;

  for (int n = start + (int)threadIdx.x; n < end; n += 256) {
    int b = bix[n];
    double x1, y1, x2, y2; bool valid;
    decode_box(anchors, deltas, isz, n, b, x1, y1, x2, y2, valid);
    float sc = valid ? logits[n] : NEGF;
    scores[n] = sc;
    if (valid) {
      int bin = score_bin(sc);
      if (b == b0)      atomicAdd(&lh[0][bin], 1u);
      else if (b == b1) atomicAdd(&lh[1][bin], 1u);
      else              atomicAdd(&hist[b * BINS + bin_slot(bin)], 1u);
    }
  }
  __syncthreads();
  for (int bin = threadIdx.x; bin < BINS; bin += 256) {
    uint32_t c0 = lh[0][bin];
    if (c0) atomicAdd(&hist[b0 * BINS + bin_slot(bin)], c0);
    if (b1 != b0) {
      uint32_t c1 = lh[1][bin];
      if (c1) atomicAdd(&hist[b1 * BINS + bin_slot(bin)], c1);
    }
  }
}

__global__ void k_scan(const uint32_t* __restrict__ hist, uint32_t* __restrict__ bstar) {
  __shared__ uint32_t s[BINS];
  __shared__ int bs;
  int b = blockIdx.x, t = threadIdx.x;
  s[t] = hist[b * BINS + bin_slot(t)];
  if (t == 0) bs = 0;
  __syncthreads();
  for (int off = 1; off < BINS; off <<= 1) {
    uint32_t v = (t + off < BINS) ? s[t + off] : 0u;
    __syncthreads();
    s[t] += v;
    __syncthreads();
  }
  if (s[t] >= PRE_K) atomicMax(&bs, t);
  __syncthreads();
  if (t == 0) bstar[b] = (uint32_t)bs;
}

// Block-aggregated compaction: each block spans 8192 contiguous elements
// (<=2 distinct batches since batch_indices is sorted), counts candidates in
// LDS, then does ONE returning global atomicAdd per (block,batch).
__global__ void __launch_bounds__(1024) k_compact(const float* __restrict__ scores,
                                                  const int* __restrict__ bix,
                                                  const uint32_t* __restrict__ bstar,
                                                  uint32_t* __restrict__ cnt,
                                                  uint64_t* __restrict__ cand, int N) {
  const int SPAN = 8192;
  int start = blockIdx.x * SPAN;
  int end = start + SPAN < N ? start + SPAN : N;
  __shared__ uint32_t lcnt[8], lbase[8];
  if (threadIdx.x < 8) lcnt[threadIdx.x] = 0u;
  __syncthreads();

  bool     predv[8];
  uint64_t keyv[8];
  uint32_t lposv[8];
  int      bv[8];
  int nt = 0;
  for (int base = start; base < end; base += 1024, nt++) {
    int n = base + (int)threadIdx.x;
    bool pred = false; int b = 0; uint64_t key = 0ull; uint32_t lp = 0u;
    if (n < end) {
      float sc = scores[n];
      if (sc > 0.5f * NEGF) {
        b = bix[n];
        if ((uint32_t)score_bin(sc) >= bstar[b]) {
          pred = true;
          key = ((uint64_t)orderf(sc) << 32) | (uint64_t)(uint32_t)(~(uint32_t)n);
          lp = atomicAdd(&lcnt[b], 1u);
        }
      }
    }
    predv[nt] = pred; keyv[nt] = key; lposv[nt] = lp; bv[nt] = b;
  }
  __syncthreads();
  if (threadIdx.x < 8) {
    uint32_t c = lcnt[threadIdx.x];
    lbase[threadIdx.x] = c ? atomicAdd(&cnt[threadIdx.x], c) : 0u;
  }
  __syncthreads();
  for (int k = 0; k < nt; k++) {
    if (predv[k]) {
      uint32_t pos = lbase[bv[k]] + lposv[k];
      if (pos < CAP) cand[(size_t)bv[k] * CAP + pos] = keyv[k];
    }
  }
}

// exact ranking of <=8192 unique u64 keys per batch; grid = B*8 blocks x 1024
__global__ void k_rank(const uint64_t* __restrict__ cand,
                       const uint32_t* __restrict__ cnt,
                       int* __restrict__ sorted_n, int* __restrict__ Cnum) {
  int b = blockIdx.x >> 3, chunk = blockIdx.x & 7, t = threadIdx.x;
  int C = (int)min(cnt[b], (uint32_t)CAP);
  int i = chunk * 1024 + t;
  uint64_t ki = (i < C) ? cand[(size_t)b * CAP + i] : 0ull;
  __shared__ uint64_t tile[1024];
  int rank = 0;
  for (int base = 0; base < C; base += 1024) {
    int j = base + t;
    tile[t] = (j < C) ? cand[(size_t)b * CAP + j] : 0ull;
    __syncthreads();
    int lim = min(1024, C - base);
    for (int jj = 0; jj < lim; jj++) rank += (tile[jj] > ki) ? 1 : 0;
    __syncthreads();
  }
  if (i < C && rank < PRE_K)
    sorted_n[b * PRE_K + rank] = (int)(~(uint32_t)(ki & 0xFFFFFFFFull));
  if (chunk == 0 && t == 0) Cnum[b] = C < PRE_K ? C : PRE_K;
}

__global__ void k_gather(const float* __restrict__ anchors,
                         const float* __restrict__ deltas,
                         const int* __restrict__ isz,
                         const int* __restrict__ sorted_n,
                         const int* __restrict__ Cnum,
                         double* __restrict__ tbox, double* __restrict__ tarea,
                         int* __restrict__ top_n, int B) {
  int idx = blockIdx.x * blockDim.x + threadIdx.x;
  if (idx >= B * PRE_K) return;
  int b = idx / PRE_K, r = idx % PRE_K;
  if (r >= Cnum[b]) return;
  int n = sorted_n[idx];
  double x1, y1, x2, y2; bool valid;
  decode_box(anchors, deltas, isz, n, b, x1, y1, x2, y2, valid);
  size_t row = (size_t)b * ROWS + r;
  tbox[row * 4 + 0] = x1;
  tbox[row * 4 + 1] = y1;
  tbox[row * 4 + 2] = x2;
  tbox[row * 4 + 3] = y2;
  tarea[row] = (x2 - x1) * (y2 - y1);
  top_n[idx] = n;
}

// Upper-triangular suppression bit-matrix: bit j of row i = (IoU(i,j)>0.7, j>i).
// grid = B*CH*CH blocks x 64 lanes; block (b, rc, cc) computes a 64x64 tile.
__global__ void __launch_bounds__(64) k_iou_mat(const double* __restrict__ tbox,
                                                const double* __restrict__ tarea,
                                                const int* __restrict__ Cnum,
                                                uint32_t* __restrict__ mask) {
  int blk = blockIdx.x;
  int cc = blk % CH;
  int rc = (blk / CH) % CH;
  int b  = blk / (CH * CH);
  if (cc < rc) return;                 // lower triangle never read
  int C = Cnum[b];
  if (rc * 64 >= C) return;            // rows pre-suppressed, never read
  int lane = threadIdx.x;

  // 48B per column box: x1,y1,x2,y2,area,pad -> b128 + b64 LDS reads
  __shared__ double cb[64][6];
  {
    size_t jrow = (size_t)b * ROWS + cc * 64 + lane;
    const double* pj = &tbox[jrow * 4];
    cb[lane][0] = pj[0]; cb[lane][1] = pj[1];
    cb[lane][2] = pj[2]; cb[lane][3] = pj[3];
    cb[lane][4] = tarea[jrow];
  }
  __syncthreads();

  int i = rc * 64 + lane;
  size_t irow = (size_t)b * ROWS + i;
  const double* pi = &tbox[irow * 4];
  double x1 = pi[0], y1 = pi[1], x2 = pi[2], y2 = pi[3];
  double ai = tarea[irow];

  uint32_t w0 = 0u, w1 = 0u;
  for (int jj = 0; jj < 64; jj++) {
    int jcol = cc * 64 + jj;
    double4 cbox = *(const double4*)&cb[jj][0];  // one ds_read_b128 x2
    double carea = cb[jj][4];
    double ix1 = fmax(x1, cbox.x);
    double iy1 = fmax(y1, cbox.y);
    double ix2 = fmin(x2, cbox.z);
    double iy2 = fmin(y2, cbox.w);
    double iw = ix2 - ix1; iw = iw > 0.0 ? iw : 0.0;
    double ih = iy2 - iy1; ih = ih > 0.0 ? ih : 0.0;
    double inter = iw * ih;
    // iou > 0.7  <=>  inter > 0.7*(ai+aj-inter+1e-9)   (denominator > 0)
    bool sup = (jcol > i) && (inter > 0.7 * (ai + carea - inter + 1e-9));
    if (jj < 32) w0 |= (uint32_t)sup << jj;
    else         w1 |= (uint32_t)sup << (jj - 32);
  }
  uint32_t* mr = &mask[irow * MASKW + 2 * cc];
  mr[0] = w0; mr[1] = w1;
}

// Greedy resolve, frontier-recomputation scheme: suppression only ever comes
// from KEPT rows, so at chunk c the 64-bit frontier is OR over kept rows j of
// mask[j][2c..2c+1] — <=1000 independent 8B loads spread over 256 threads
// (one latency round, lines reused across 8 consecutive chunks), reduced via
// shfl + 8 LDS atomicOrs. Wave0 runs the pick chain with prefetched diag.
__global__ void __launch_bounds__(256) k_nms_reduce(const uint32_t* __restrict__ mask,
                                                    const int* __restrict__ Cnum,
                                                    int* __restrict__ keep,
                                                    int* __restrict__ kept_count) {
  int b = blockIdx.x;
  int t = threadIdx.x;
  int wave = t >> 6, lane = t & 63;
  int C = Cnum[b];
  const uint32_t* M = mask + (size_t)b * ROWS * MASKW;

  __shared__ uint32_t s_f[2][2];       // double-buffered frontier accumulators
  __shared__ uint32_t kept_s[POST_K];  // kept row indices (block-local list)
  __shared__ uint64_t s_kept;          // this chunk's (capped) kept mask
  if (t < 4) ((uint32_t*)s_f)[t] = 0u;

  // wave0: diag tile words for chunk 0 (row lane, words 0..1)
  uint32_t d0 = 0u, d1 = 0u;
  if (wave == 0) {
    uint2 v = *(const uint2*)(M + (size_t)lane * MASKW);
    d0 = v.x; d1 = v.y;
  }
  __syncthreads();

  int nkept = 0;
  for (int c = 0; c < CH; c++) {
    int base = c * 64;
    if (base >= C) break;
    int cb = c & 1;
    if (t == 0) { s_f[cb ^ 1][0] = 0u; s_f[cb ^ 1][1] = 0u; }

    // frontier: OR over kept rows' words 2c, 2c+1
    uint32_t f0 = 0u, f1 = 0u;
    for (int k = t; k < nkept; k += 256) {
      uint2 v = *(const uint2*)(M + (size_t)kept_s[k] * MASKW + 2 * c);
      f0 |= v.x; f1 |= v.y;
    }
#pragma unroll
    for (int off = 32; off > 0; off >>= 1) {
      f0 |= (uint32_t)__shfl_xor((int)f0, off, 64);
      f1 |= (uint32_t)__shfl_xor((int)f1, off, 64);
    }
    if (lane == 0 && (f0 | f1)) {
      atomicOr(&s_f[cb][0], f0);
      atomicOr(&s_f[cb][1], f1);
    }
    __syncthreads();

    if (wave == 0) {
      uint64_t sup = (uint64_t)s_f[cb][0] | ((uint64_t)s_f[cb][1] << 32);
      int rem = C - base;                       // > 0 here
      if (rem < 64) sup |= ~((1ull << rem) - 1ull);
      uint64_t diag = (uint64_t)d0 | ((uint64_t)d1 << 32);
      // prefetch next chunk's diag (static addresses)
      int cn = (c + 1 < CH) ? c + 1 : c;
      uint2 vn = *(const uint2*)(M + (size_t)(cn * 64 + lane) * MASKW + 2 * cn);

      uint64_t keptMask = 0ull;
      uint64_t alive = ~sup;
      uint64_t m = alive;
      while (m) {
        int i = __builtin_ctzll(m);
        keptMask |= 1ull << i;
        uint64_t d = (uint64_t)__shfl((long long)diag, i, 64);
        sup |= d | (1ull << i);
        m = alive & ~sup;
      }
      // cap to POST_K total picks (greedy stops at exactly POST_K)
      int allowed = POST_K - nkept;
      int pc = __popcll(keptMask);
      while (pc > allowed) {                     // clear highest picks (rare)
        keptMask &= ~(1ull << (63 - __builtin_clzll(keptMask)));
        pc--;
      }
      if (lane == 0) s_kept = keptMask;
      if ((keptMask >> lane) & 1ull) {
        int pos = nkept + __popcll(keptMask & ((1ull << lane) - 1ull));
        keep[b * POST_K + pos] = base + lane;
        kept_s[pos] = (uint32_t)(base + lane);
      }
      d0 = vn.x; d1 = vn.y;
    }
    __syncthreads();

    nkept += __popcll(s_kept);
    if (nkept >= POST_K) break;
  }
  if (t == 0) kept_count[b] = nkept;
}

__global__ void k_output(const int* __restrict__ keep,
                         const int* __restrict__ kept_count,
                         const int* __restrict__ top_n,
                         const double* __restrict__ tbox,
                         const float* __restrict__ logits,
                         const float* __restrict__ deltas,
                         float* __restrict__ out, int B) {
  int idx = blockIdx.x * blockDim.x + threadIdx.x;
  int M = B * POST_K;
  if (idx >= M) return;
  int b = idx / POST_K, s = idx % POST_K;
  float p0 = 0.f, p1 = 0.f, p2 = 0.f, p3 = 0.f;
  float ob = 0.f, d0 = 0.f, d1 = 0.f, d2 = 0.f, d3 = 0.f;
  float bi = -1.0f, okv = 0.0f;
  if (s < kept_count[b]) {
    int j = keep[b * POST_K + s];
    int n = top_n[b * PRE_K + j];
    const double* p = &tbox[((size_t)b * ROWS + j) * 4];
    p0 = (float)p[0]; p1 = (float)p[1]; p2 = (float)p[2]; p3 = (float)p[3];
    ob = logits[n];
    d0 = deltas[4 * n + 0]; d1 = deltas[4 * n + 1];
    d2 = deltas[4 * n + 2]; d3 = deltas[4 * n + 3];
    bi = (float)b; okv = 1.0f;
  }
  out[idx * 4 + 0] = p0;
  out[idx * 4 + 1] = p1;
  out[idx * 4 + 2] = p2;
  out[idx * 4 + 3] = p3;
  out[4 * M + idx] = bi;
  out[5 * M + idx] = ob;
  out[6 * M + idx * 4 + 0] = d0;
  out[6 * M + idx * 4 + 1] = d1;
  out[6 * M + idx * 4 + 2] = d2;
  out[6 * M + idx * 4 + 3] = d3;
  out[10 * M + idx] = okv;
}

// ---- launch -----------------------------------------------------------------

extern "C" void kernel_launch(void* const* d_in, const int* in_sizes, int n_in,
                              void* d_out, int out_size, void* d_ws, size_t ws_size,
                              hipStream_t stream) {
  const float* anchors = (const float*)d_in[0];
  const int*   bix     = (const int*)d_in[1];
  const int*   isz     = (const int*)d_in[2];
  const float* logits  = (const float*)d_in[3];
  const float* deltas  = (const float*)d_in[4];
  float* out = (float*)d_out;

  int N = in_sizes[1];
  int B = in_sizes[2] / 2;

  uintptr_t p = (uintptr_t)d_ws;
  double*   tbox   = (double*)p;    p += (size_t)B * ROWS * 4 * sizeof(double);
  double*   tarea  = (double*)p;    p += (size_t)B * ROWS * sizeof(double);
  uint64_t* cand   = (uint64_t*)p;  p += (size_t)B * CAP * sizeof(uint64_t);
  float*    scores = (float*)p;     p += (size_t)N * sizeof(float);
  uint32_t* hist   = (uint32_t*)p;  p += (size_t)B * BINS * sizeof(uint32_t);
  int*      sorted_n = (int*)p;     p += (size_t)B * PRE_K * sizeof(int);
  int*      top_n    = (int*)p;     p += (size_t)B * PRE_K * sizeof(int);
  int*      keep     = (int*)p;     p += (size_t)B * POST_K * sizeof(int);
  uint32_t* cnt      = (uint32_t*)p; p += (size_t)B * sizeof(uint32_t);
  uint32_t* bstar    = (uint32_t*)p; p += (size_t)B * sizeof(uint32_t);
  int*      Cnum     = (int*)p;      p += (size_t)B * sizeof(int);
  int*      kept_cnt = (int*)p;      p += (size_t)B * sizeof(int);
  p = (p + 255) & ~(uintptr_t)255;
  uint32_t* mask     = (uint32_t*)p; p += (size_t)B * ROWS * MASKW * sizeof(uint32_t);
  (void)ws_size; (void)n_in; (void)out_size;

  int initN = B * BINS;
  k_init<<<(initN + 255) / 256, 256, 0, stream>>>(hist, cnt, B);
  k_score<<<(N + 4095) / 4096, 256, 0, stream>>>(anchors, bix, isz, logits, deltas,
                                                 scores, hist, N);
  k_scan<<<B, BINS, 0, stream>>>(hist, bstar);
  k_compact<<<(N + 8191) / 8192, 1024, 0, stream>>>(scores, bix, bstar, cnt, cand, N);
  k_rank<<<B * 8, 1024, 0, stream>>>(cand, cnt, sorted_n, Cnum);
  k_gather<<<(B * PRE_K + 255) / 256, 256, 0, stream>>>(anchors, deltas, isz,
                                                        sorted_n, Cnum, tbox,
                                                        tarea, top_n, B);
  k_iou_mat<<<B * CH * CH, 64, 0, stream>>>(tbox, tarea, Cnum, mask);
  k_nms_reduce<<<B, 256, 0, stream>>>(mask, Cnum, keep, kept_cnt);
  k_output<<<(B * POST_K + 255) / 256, 256, 0, stream>>>(keep, kept_cnt, top_n,
                                                         tbox, logits, deltas,
                                                         out, B);
}